// Round 2
// baseline (1269.651 us; speedup 1.0000x reference)
//
#include <hip/hip_runtime.h>
#include <math.h>

#define S_LEN  2048
#define NH     16
#define HD     64
#define DMODEL 1024
#define BATCH  4
#define M_TOK  (BATCH * S_LEN)   // 8192

typedef __bf16 bf16x8 __attribute__((ext_vector_type(8)));
typedef float  floatx4 __attribute__((ext_vector_type(4)));

typedef __attribute__((address_space(1))) const void cg_void;
typedef __attribute__((address_space(3))) void lds_void;

__device__ __forceinline__ void gload16(const void* g, void* l) {
    // async global->LDS, 16B per lane; LDS dest = wave-uniform base + lane*16
    __builtin_amdgcn_global_load_lds((cg_void*)g, (lds_void*)l, 16, 0, 0);
}

__device__ __forceinline__ unsigned short f2bf(float f) {   // RNE f32->bf16
    unsigned int u = __builtin_bit_cast(unsigned int, f);
    u = (u + 0x7FFF + ((u >> 16) & 1)) >> 16;
    return (unsigned short)u;
}

// ---------------- RoPE cos/sin table: [S_LEN][32] each ----------------
__global__ void rope_table_kernel(float* __restrict__ cs, float* __restrict__ sn) {
    int idx = blockIdx.x * 256 + threadIdx.x;    // S_LEN*32 = 65536
    int j = idx & 31;
    int s = idx >> 5;
    double invf = pow(10000.0, -(double)j / 32.0);
    double a = (double)s * invf;
    cs[idx] = (float)cos(a);
    sn[idx] = (float)sin(a);
}

// ---------------- apply RoPE in-place to q and k (heads layout fp32) ----------------
__global__ void rope_apply_kernel(float* __restrict__ q, float* __restrict__ k,
                                  const float* __restrict__ cs, const float* __restrict__ sn) {
    int idx = blockIdx.x * 256 + threadIdx.x;   // B*NH*S*32 = 4194304
    int d   = idx & 31;
    int row = idx >> 5;            // (b*NH+h)*S + s
    int s   = row & (S_LEN - 1);
    float c  = cs[s * 32 + d];
    float si = sn[s * 32 + d];
    size_t base = (size_t)row * HD;
    float q1 = q[base + d], q2 = q[base + d + 32];
    q[base + d]      = q1 * c - q2 * si;
    q[base + d + 32] = q2 * c + q1 * si;
    float k1 = k[base + d], k2 = k[base + d + 32];
    k[base + d]      = k1 * c - k2 * si;
    k[base + d + 32] = k2 * c + k1 * si;
}

// ---------------- fp32 -> bf16 convert of x ----------------
__global__ void convert_x_kernel(const float* __restrict__ x, unsigned short* __restrict__ xb) {
    int idx = blockIdx.x * 256 + threadIdx.x;   // 2097152 threads x 4 elems
    float4 a = *reinterpret_cast<const float4*>(&x[(size_t)idx * 4]);
    ushort4 o;
    o.x = f2bf(a.x); o.y = f2bf(a.y); o.z = f2bf(a.z); o.w = f2bf(a.w);
    *reinterpret_cast<ushort4*>(&xb[(size_t)idx * 4]) = o;
}

// ---------------- W [K][N] fp32  ->  Wt [N][K] bf16 ----------------
__global__ void convert_transpose_w(const float* __restrict__ w, unsigned short* __restrict__ wt) {
    __shared__ float tile[32][33];
    int tx  = threadIdx.x & 31;
    int ty8 = threadIdx.x >> 5;          // 0..7
    int n0 = blockIdx.x * 32;
    int k0 = blockIdx.y * 32;
    #pragma unroll
    for (int i = 0; i < 4; ++i)
        tile[ty8 + i * 8][tx] = w[(size_t)(k0 + ty8 + i * 8) * DMODEL + n0 + tx];
    __syncthreads();
    #pragma unroll
    for (int i = 0; i < 4; ++i)
        wt[(size_t)(n0 + ty8 + i * 8) * DMODEL + k0 + tx] = f2bf(tile[tx][ty8 + i * 8]);
}

// ---------------- bf16 MFMA GEMM: C(MxN) = A(MxK) @ Wt(NxK)^T + bias ----------------
// A bf16 [M][K], Bt bf16 [N][K] (contiguous-K for both fragment reads).
// MODE 0: write fp32 heads layout [(b*NH+h)][s][d]   (q,k,v)
// MODE 1: write fp32 row-major [m][n] * (mask[m]!=0)  (final projection)
template<int MODE>
__global__ __launch_bounds__(256)
void gemm_mfma(const unsigned short* __restrict__ A, const unsigned short* __restrict__ Bt,
               const float* __restrict__ bias, const int* __restrict__ mask,
               float* __restrict__ C)
{
    constexpr int K = DMODEL;
    __shared__ unsigned short As[2][128 * 32];   // [row][k] 8 KB each buf
    __shared__ unsigned short Bs[2][128 * 32];   // [col][k]

    const int tid  = threadIdx.x;
    const int lane = tid & 63;
    const int w    = tid >> 6;        // wave 0..3
    const int wm   = w >> 1;          // wave row 0..1
    const int wn   = w & 1;           // wave col 0..1
    const int row0 = blockIdx.y * 128;
    const int col0 = blockIdx.x * 128;

    const int sr  = lane >> 2;        // staging row within 16-row chunk
    const int sk8 = (lane & 3) * 8;   // staging k element offset
    const int fr  = lane & 15;        // fragment row/col
    const int fk  = (lane >> 4) * 8;  // fragment k offset

    floatx4 acc[4][4] = {};

    // prologue stage k0=0 into buf 0
    #pragma unroll
    for (int t = 0; t < 2; ++t) {
        const int chunk = w * 32 + t * 16;
        gload16(A  + (size_t)(row0 + chunk + sr) * K + sk8, &As[0][chunk * 32]);
        gload16(Bt + (size_t)(col0 + chunk + sr) * K + sk8, &Bs[0][chunk * 32]);
    }

    for (int kt = 0; kt < K / 32; ++kt) {
        __syncthreads();   // compiler drains vmcnt before barrier -> staged tile visible
        if (kt + 1 < K / 32) {
            const int nb = (kt + 1) & 1;
            const int k0 = (kt + 1) * 32;
            #pragma unroll
            for (int t = 0; t < 2; ++t) {
                const int chunk = w * 32 + t * 16;
                gload16(A  + (size_t)(row0 + chunk + sr) * K + k0 + sk8, &As[nb][chunk * 32]);
                gload16(Bt + (size_t)(col0 + chunk + sr) * K + k0 + sk8, &Bs[nb][chunk * 32]);
            }
        }
        const int cur = kt & 1;
        bf16x8 av[4], bv[4];
        #pragma unroll
        for (int m = 0; m < 4; ++m)
            av[m] = *reinterpret_cast<const bf16x8*>(&As[cur][(wm * 64 + m * 16 + fr) * 32 + fk]);
        #pragma unroll
        for (int n = 0; n < 4; ++n)
            bv[n] = *reinterpret_cast<const bf16x8*>(&Bs[cur][(wn * 64 + n * 16 + fr) * 32 + fk]);
        #pragma unroll
        for (int m = 0; m < 4; ++m)
            #pragma unroll
            for (int n = 0; n < 4; ++n)
                acc[m][n] = __builtin_amdgcn_mfma_f32_16x16x32_bf16(av[m], bv[n], acc[m][n], 0, 0, 0);
    }

    // epilogue: lane holds D[(lane>>4)*4 + r][lane&15] per fragment
    const int rbase = lane >> 4;    // *4
    #pragma unroll
    for (int m = 0; m < 4; ++m) {
        #pragma unroll
        for (int n = 0; n < 4; ++n) {
            const int c = col0 + wn * 64 + n * 16 + fr;
            const float bc = bias[c];
            #pragma unroll
            for (int r = 0; r < 4; ++r) {
                const int mr = row0 + wm * 64 + m * 16 + rbase * 4 + r;
                const float v = acc[m][n][r] + bc;
                if (MODE == 0) {
                    const int bb = mr >> 11;
                    const int ss = mr & (S_LEN - 1);
                    const int h  = c >> 6;
                    const int d  = c & 63;
                    C[(((size_t)(bb * NH + h)) * S_LEN + ss) * HD + d] = v;
                } else {
                    C[(size_t)mr * DMODEL + c] = mask[mr] ? v : 0.0f;
                }
            }
        }
    }
}

// ---------------- flash attention, fp32 compute, bf16 ctx output ----------------
__global__ __launch_bounds__(256)
void attn_kernel(const float* __restrict__ qg, const float* __restrict__ kg,
                 const float* __restrict__ vg, const int* __restrict__ mask,
                 unsigned short* __restrict__ ctxb)
{
    __shared__ float Qs[64][68];    // Q^T: Qs[d][i], pre-scaled by 1/8
    __shared__ float KPs[64][68];   // K^T during QK^T, then P^T
    __shared__ float Vs[64][68];    // natural [j][d]

    const int tid = threadIdx.x;
    const int tx  = tid & 15;
    const int ty  = tid >> 4;
    const int bh  = blockIdx.y;     // b*NH + h
    const int b   = bh >> 4;
    const int h   = bh & 15;
    const int q0  = blockIdx.x * 64;
    const size_t headbase = (size_t)bh * S_LEN * HD;
    const int* mrow_g = mask + b * S_LEN;

    {   // load Q tile transposed + scaled
        const int i  = tid >> 2;
        const int dc = (tid & 3) * 16;
        const float* src = qg + headbase + (size_t)(q0 + i) * HD + dc;
        #pragma unroll
        for (int c = 0; c < 16; c += 4) {
            float4 t4 = *reinterpret_cast<const float4*>(src + c);
            Qs[dc + c + 0][i] = t4.x * 0.125f;
            Qs[dc + c + 1][i] = t4.y * 0.125f;
            Qs[dc + c + 2][i] = t4.z * 0.125f;
            Qs[dc + c + 3][i] = t4.w * 0.125f;
        }
    }

    float o[4][4] = {};
    float mrow[4] = {-INFINITY, -INFINITY, -INFINITY, -INFINITY};
    float lrow[4] = {};

    for (int kt = 0; kt < S_LEN / 64; ++kt) {
        {   // load K^T and V
            const int j  = tid >> 2;
            const int dc = (tid & 3) * 16;
            const float* ksrc = kg + headbase + (size_t)(kt * 64 + j) * HD + dc;
            const float* vsrc = vg + headbase + (size_t)(kt * 64 + j) * HD + dc;
            #pragma unroll
            for (int c = 0; c < 16; c += 4) {
                float4 t4 = *reinterpret_cast<const float4*>(ksrc + c);
                KPs[dc + c + 0][j] = t4.x;
                KPs[dc + c + 1][j] = t4.y;
                KPs[dc + c + 2][j] = t4.z;
                KPs[dc + c + 3][j] = t4.w;
                *reinterpret_cast<float4*>(&Vs[j][dc + c]) =
                    *reinterpret_cast<const float4*>(vsrc + c);
            }
        }
        __syncthreads();

        float sacc[4][4] = {};
        #pragma unroll 8
        for (int d = 0; d < 64; ++d) {
            float ra[4], rb[4];
            *reinterpret_cast<float4*>(ra) = *reinterpret_cast<const float4*>(&Qs[d][ty * 4]);
            *reinterpret_cast<float4*>(rb) = *reinterpret_cast<const float4*>(&KPs[d][tx * 4]);
            #pragma unroll
            for (int i = 0; i < 4; ++i)
                #pragma unroll
                for (int j = 0; j < 4; ++j)
                    sacc[i][j] = fmaf(ra[i], rb[j], sacc[i][j]);
        }
        __syncthreads();   // K fully consumed before KPs is reused for P^T

        #pragma unroll
        for (int j = 0; j < 4; ++j) {
            if (mrow_g[kt * 64 + tx * 4 + j] == 0) {
                #pragma unroll
                for (int i = 0; i < 4; ++i) sacc[i][j] = -3.4028234663852886e38f;
            }
        }

        float p[4][4];
        #pragma unroll
        for (int i = 0; i < 4; ++i) {
            float mx = fmaxf(fmaxf(sacc[i][0], sacc[i][1]), fmaxf(sacc[i][2], sacc[i][3]));
            mx = fmaxf(mx, __shfl_xor(mx, 1));
            mx = fmaxf(mx, __shfl_xor(mx, 2));
            mx = fmaxf(mx, __shfl_xor(mx, 4));
            mx = fmaxf(mx, __shfl_xor(mx, 8));
            float mnew = fmaxf(mrow[i], mx);
            float f = __expf(mrow[i] - mnew);
            float rs = 0.0f;
            #pragma unroll
            for (int j = 0; j < 4; ++j) { p[i][j] = __expf(sacc[i][j] - mnew); rs += p[i][j]; }
            rs += __shfl_xor(rs, 1);
            rs += __shfl_xor(rs, 2);
            rs += __shfl_xor(rs, 4);
            rs += __shfl_xor(rs, 8);
            lrow[i] = lrow[i] * f + rs;
            mrow[i] = mnew;
            #pragma unroll
            for (int d = 0; d < 4; ++d) o[i][d] *= f;
        }

        #pragma unroll
        for (int i = 0; i < 4; ++i)
            #pragma unroll
            for (int j = 0; j < 4; ++j)
                KPs[tx * 4 + j][ty * 4 + i] = p[i][j];   // P^T
        __syncthreads();

        #pragma unroll 8
        for (int jl = 0; jl < 64; ++jl) {
            float rp[4], rv[4];
            *reinterpret_cast<float4*>(rp) = *reinterpret_cast<const float4*>(&KPs[jl][ty * 4]);
            *reinterpret_cast<float4*>(rv) = *reinterpret_cast<const float4*>(&Vs[jl][tx * 4]);
            #pragma unroll
            for (int i = 0; i < 4; ++i)
                #pragma unroll
                for (int d = 0; d < 4; ++d)
                    o[i][d] = fmaf(rp[i], rv[d], o[i][d]);
        }
        __syncthreads();   // P,V consumed before next tile's loads
    }

    #pragma unroll
    for (int i = 0; i < 4; ++i) {
        int row = q0 + ty * 4 + i;
        float inv = 1.0f / lrow[i];
        ushort4 ov;
        ov.x = f2bf(o[i][0] * inv);
        ov.y = f2bf(o[i][1] * inv);
        ov.z = f2bf(o[i][2] * inv);
        ov.w = f2bf(o[i][3] * inv);
        *reinterpret_cast<ushort4*>(&ctxb[((size_t)b * S_LEN + row) * DMODEL + h * HD + tx * 4]) = ov;
    }
}

extern "C" void kernel_launch(void* const* d_in, const int* in_sizes, int n_in,
                              void* d_out, int out_size, void* d_ws, size_t ws_size,
                              hipStream_t stream) {
    const float* x    = (const float*)d_in[0];
    const int*   mask = (const int*)d_in[1];     // bool normalized to int32 by harness
    const float* wq = (const float*)d_in[2];
    const float* bq = (const float*)d_in[3];
    const float* wk = (const float*)d_in[4];
    const float* bk = (const float*)d_in[5];
    const float* wv = (const float*)d_in[6];
    const float* bv = (const float*)d_in[7];
    const float* wo = (const float*)d_in[8];
    const float* bo = (const float*)d_in[9];
    float* out = (float*)d_out;

    // workspace layout
    const size_t QKV = (size_t)M_TOK * DMODEL;   // 8388608
    float* qb = (float*)d_ws;
    float* kb = qb + QKV;
    float* vb = kb + QKV;
    float* cs = vb + QKV;
    float* sn = cs + (size_t)S_LEN * 32;
    unsigned short* xb   = (unsigned short*)(sn + (size_t)S_LEN * 32);
    unsigned short* wtq  = xb  + QKV;
    unsigned short* wtk  = wtq + (size_t)DMODEL * DMODEL;
    unsigned short* wtv  = wtk + (size_t)DMODEL * DMODEL;
    unsigned short* wto  = wtv + (size_t)DMODEL * DMODEL;
    unsigned short* ctxb = wto + (size_t)DMODEL * DMODEL;
    // total ~143 MB

    rope_table_kernel<<<S_LEN * 32 / 256, 256, 0, stream>>>(cs, sn);
    convert_x_kernel<<<QKV / (256 * 4), 256, 0, stream>>>(x, xb);

    dim3 tgrid(DMODEL / 32, DMODEL / 32);
    convert_transpose_w<<<tgrid, 256, 0, stream>>>(wq, wtq);
    convert_transpose_w<<<tgrid, 256, 0, stream>>>(wk, wtk);
    convert_transpose_w<<<tgrid, 256, 0, stream>>>(wv, wtv);
    convert_transpose_w<<<tgrid, 256, 0, stream>>>(wo, wto);

    dim3 ggrid(DMODEL / 128, M_TOK / 128);   // (8, 64)
    gemm_mfma<0><<<ggrid, 256, 0, stream>>>(xb, wtq, bq, nullptr, qb);
    gemm_mfma<0><<<ggrid, 256, 0, stream>>>(xb, wtk, bk, nullptr, kb);
    gemm_mfma<0><<<ggrid, 256, 0, stream>>>(xb, wtv, bv, nullptr, vb);

    rope_apply_kernel<<<BATCH * NH * S_LEN * 32 / 256, 256, 0, stream>>>(qb, kb, cs, sn);

    dim3 agrid(S_LEN / 64, BATCH * NH);      // (32, 64)
    attn_kernel<<<agrid, 256, 0, stream>>>(qb, kb, vb, mask, ctxb);

    gemm_mfma<1><<<ggrid, 256, 0, stream>>>(ctxb, wto, bo, mask, out);
}

// Round 3
// 516.416 us; speedup vs baseline: 2.4586x; 2.4586x over previous
//
#include <hip/hip_runtime.h>
#include <math.h>

#define S_LEN  2048
#define NH     16
#define HD     64
#define DMODEL 1024
#define BATCH  4
#define M_TOK  (BATCH * S_LEN)   // 8192

typedef __bf16 bf16x8 __attribute__((ext_vector_type(8)));
typedef float  floatx4 __attribute__((ext_vector_type(4)));

typedef __attribute__((address_space(1))) const void cg_void;
typedef __attribute__((address_space(3))) void lds_void;

__device__ __forceinline__ void gload16(const void* g, void* l) {
    // async global->LDS, 16B per lane; LDS dest = wave-uniform base + lane*16
    __builtin_amdgcn_global_load_lds((cg_void*)g, (lds_void*)l, 16, 0, 0);
}

__device__ __forceinline__ unsigned short f2bf(float f) {   // RNE f32->bf16
    unsigned int u = __builtin_bit_cast(unsigned int, f);
    u = (u + 0x7FFF + ((u >> 16) & 1)) >> 16;
    return (unsigned short)u;
}

// ---------------- RoPE cos/sin table: [S_LEN][32] each ----------------
__global__ void rope_table_kernel(float* __restrict__ cs, float* __restrict__ sn) {
    int idx = blockIdx.x * 256 + threadIdx.x;    // S_LEN*32 = 65536
    int j = idx & 31;
    int s = idx >> 5;
    double invf = pow(10000.0, -(double)j / 32.0);
    double a = (double)s * invf;
    cs[idx] = (float)cos(a);
    sn[idx] = (float)sin(a);
}

// ---- apply RoPE to fp32 q,k heads layout; emit bf16 (q pre-scaled by 0.125) ----
__global__ void rope_apply_bf16(const float* __restrict__ q, const float* __restrict__ k,
                                const float* __restrict__ cs, const float* __restrict__ sn,
                                unsigned short* __restrict__ qo, unsigned short* __restrict__ ko) {
    int idx = blockIdx.x * 256 + threadIdx.x;   // B*NH*S*32 = 4194304
    int d   = idx & 31;
    int row = idx >> 5;            // (b*NH+h)*S + s
    int s   = row & (S_LEN - 1);
    float c  = cs[s * 32 + d];
    float si = sn[s * 32 + d];
    size_t base = (size_t)row * HD;
    float q1 = q[base + d], q2 = q[base + d + 32];
    qo[base + d]      = f2bf((q1 * c - q2 * si) * 0.125f);
    qo[base + d + 32] = f2bf((q2 * c + q1 * si) * 0.125f);
    float k1 = k[base + d], k2 = k[base + d + 32];
    ko[base + d]      = f2bf(k1 * c - k2 * si);
    ko[base + d + 32] = f2bf(k2 * c + k1 * si);
}

// ---------------- fp32 -> bf16 convert of x ----------------
__global__ void convert_x_kernel(const float* __restrict__ x, unsigned short* __restrict__ xb) {
    int idx = blockIdx.x * 256 + threadIdx.x;
    float4 a = *reinterpret_cast<const float4*>(&x[(size_t)idx * 4]);
    ushort4 o;
    o.x = f2bf(a.x); o.y = f2bf(a.y); o.z = f2bf(a.z); o.w = f2bf(a.w);
    *reinterpret_cast<ushort4*>(&xb[(size_t)idx * 4]) = o;
}

// ---------------- W [K][N] fp32  ->  Wt [N][K] bf16 ----------------
__global__ void convert_transpose_w(const float* __restrict__ w, unsigned short* __restrict__ wt) {
    __shared__ float tile[32][33];
    int tx  = threadIdx.x & 31;
    int ty8 = threadIdx.x >> 5;          // 0..7
    int n0 = blockIdx.x * 32;
    int k0 = blockIdx.y * 32;
    #pragma unroll
    for (int i = 0; i < 4; ++i)
        tile[ty8 + i * 8][tx] = w[(size_t)(k0 + ty8 + i * 8) * DMODEL + n0 + tx];
    __syncthreads();
    #pragma unroll
    for (int i = 0; i < 4; ++i)
        wt[(size_t)(n0 + ty8 + i * 8) * DMODEL + k0 + tx] = f2bf(tile[tx][ty8 + i * 8]);
}

// ---------------- bf16 MFMA GEMM: C(MxN) = A(MxK) @ Wt(NxK)^T + bias ----------------
// MODE 0: fp32 heads layout [(b*NH+h)][s][d]           (q,k before RoPE)
// MODE 1: fp32 row-major [m][n] * (mask[m]!=0)          (final projection)
// MODE 2: bf16 V^T layout [(b*NH+h)][d][s]              (v, no RoPE)
template<int MODE>
__global__ __launch_bounds__(256)
void gemm_mfma(const unsigned short* __restrict__ A, const unsigned short* __restrict__ Bt,
               const float* __restrict__ bias, const int* __restrict__ mask,
               float* __restrict__ C)
{
    constexpr int K = DMODEL;
    __shared__ unsigned short As[2][128 * 32];
    __shared__ unsigned short Bs[2][128 * 32];

    const int tid  = threadIdx.x;
    const int lane = tid & 63;
    const int w    = tid >> 6;
    const int wm   = w >> 1;
    const int wn   = w & 1;
    const int row0 = blockIdx.y * 128;
    const int col0 = blockIdx.x * 128;

    const int sr  = lane >> 2;
    const int sk8 = (lane & 3) * 8;
    const int fr  = lane & 15;
    const int fk  = (lane >> 4) * 8;

    floatx4 acc[4][4] = {};

    #pragma unroll
    for (int t = 0; t < 2; ++t) {
        const int chunk = w * 32 + t * 16;
        gload16(A  + (size_t)(row0 + chunk + sr) * K + sk8, &As[0][chunk * 32]);
        gload16(Bt + (size_t)(col0 + chunk + sr) * K + sk8, &Bs[0][chunk * 32]);
    }

    for (int kt = 0; kt < K / 32; ++kt) {
        __syncthreads();
        if (kt + 1 < K / 32) {
            const int nb = (kt + 1) & 1;
            const int k0 = (kt + 1) * 32;
            #pragma unroll
            for (int t = 0; t < 2; ++t) {
                const int chunk = w * 32 + t * 16;
                gload16(A  + (size_t)(row0 + chunk + sr) * K + k0 + sk8, &As[nb][chunk * 32]);
                gload16(Bt + (size_t)(col0 + chunk + sr) * K + k0 + sk8, &Bs[nb][chunk * 32]);
            }
        }
        const int cur = kt & 1;
        bf16x8 av[4], bv[4];
        #pragma unroll
        for (int m = 0; m < 4; ++m)
            av[m] = *reinterpret_cast<const bf16x8*>(&As[cur][(wm * 64 + m * 16 + fr) * 32 + fk]);
        #pragma unroll
        for (int n = 0; n < 4; ++n)
            bv[n] = *reinterpret_cast<const bf16x8*>(&Bs[cur][(wn * 64 + n * 16 + fr) * 32 + fk]);
        #pragma unroll
        for (int m = 0; m < 4; ++m)
            #pragma unroll
            for (int n = 0; n < 4; ++n)
                acc[m][n] = __builtin_amdgcn_mfma_f32_16x16x32_bf16(av[m], bv[n], acc[m][n], 0, 0, 0);
    }

    const int rbase = lane >> 4;
    #pragma unroll
    for (int m = 0; m < 4; ++m) {
        #pragma unroll
        for (int n = 0; n < 4; ++n) {
            const int c = col0 + wn * 64 + n * 16 + fr;
            const float bc = bias[c];
            if (MODE == 2) {
                const int mr0 = row0 + wm * 64 + m * 16 + rbase * 4;
                const int bb  = mr0 >> 11;
                const int ss  = mr0 & (S_LEN - 1);
                const int h   = c >> 6;
                const int d   = c & 63;
                ushort4 pk;
                pk.x = f2bf(acc[m][n][0] + bc);
                pk.y = f2bf(acc[m][n][1] + bc);
                pk.z = f2bf(acc[m][n][2] + bc);
                pk.w = f2bf(acc[m][n][3] + bc);
                *reinterpret_cast<ushort4*>(
                    &((unsigned short*)C)[(((size_t)(bb * NH + h)) * HD + d) * S_LEN + ss]) = pk;
            } else {
                #pragma unroll
                for (int r = 0; r < 4; ++r) {
                    const int mr = row0 + wm * 64 + m * 16 + rbase * 4 + r;
                    const float v = acc[m][n][r] + bc;
                    if (MODE == 0) {
                        const int bb = mr >> 11;
                        const int ss = mr & (S_LEN - 1);
                        const int h  = c >> 6;
                        const int d  = c & 63;
                        C[(((size_t)(bb * NH + h)) * S_LEN + ss) * HD + d] = v;
                    } else {
                        C[(size_t)mr * DMODEL + c] = mask[mr] ? v : 0.0f;
                    }
                }
            }
        }
    }
}

// ---------------- MFMA flash attention ----------------
// qbf [bh][s][64] bf16 (pre-scaled), kbf [bh][s][64] bf16, vtb [bh][d][s] bf16
// block: 256 thr = 4 waves, 128 q-rows (32/wave); 64-key tiles
__global__ __launch_bounds__(256)
void attn_mfma_kernel(const unsigned short* __restrict__ qbf,
                      const unsigned short* __restrict__ kbf,
                      const unsigned short* __restrict__ vtb,
                      const int* __restrict__ mask,
                      unsigned short* __restrict__ ctxb)
{
    __shared__ unsigned short Ks[2][64 * 64];   // [key][d], source-swizzled
    __shared__ unsigned short Vs[2][64 * 64];   // [d][key], source-swizzled
    __shared__ unsigned short Ps[4][2048];      // per-wave fragment-major P

    const int tid  = threadIdx.x;
    const int lane = tid & 63;
    const int w    = tid >> 6;
    const int bh   = blockIdx.y;
    const int b    = bh >> 4;
    const int h    = bh & 15;
    const int q0   = blockIdx.x * 128 + w * 32;
    const size_t hb = (size_t)bh * S_LEN * HD;
    const int* mrow_g = mask + b * S_LEN;

    const int fr  = lane & 15;
    const int hi  = lane >> 4;
    const int lo  = lane & 15;
    const int fk8 = hi * 8;                 // fragment k elem offset
    const int srow   = lane >> 3;           // staging row within 8-row group
    const int schunk = (lane & 7) ^ srow;   // pre-swizzled source 16B chunk

    // Q fragments (32 rows x 64 d per wave), from global
    bf16x8 aq[2][2];
    #pragma unroll
    for (int m = 0; m < 2; ++m)
        #pragma unroll
        for (int ks = 0; ks < 2; ++ks)
            aq[m][ks] = *reinterpret_cast<const bf16x8*>(
                &qbf[hb + (size_t)(q0 + m * 16 + fr) * HD + ks * 32 + fk8]);

    floatx4 oacc[2][4] = {};
    float mrow[2][4], lrow[2][4];
    #pragma unroll
    for (int m = 0; m < 2; ++m)
        #pragma unroll
        for (int r = 0; r < 4; ++r) { mrow[m][r] = -INFINITY; lrow[m][r] = 0.0f; }

    #define STAGE(KT, BUF)                                                              \
        _Pragma("unroll")                                                               \
        for (int t = 0; t < 2; ++t) {                                                   \
            const int r0 = (w * 2 + t) * 8;                                             \
            gload16(kbf + hb + (size_t)((KT) * 64 + r0 + srow) * HD + schunk * 8,       \
                    &Ks[BUF][r0 * 64]);                                                 \
            gload16(vtb + ((size_t)bh * HD + r0 + srow) * S_LEN + (KT) * 64 + schunk * 8,\
                    &Vs[BUF][r0 * 64]);                                                 \
        }

    STAGE(0, 0)

    for (int kt = 0; kt < S_LEN / 64; ++kt) {
        __syncthreads();           // staged tile kt visible; prev reads retired
        if (kt + 1 < S_LEN / 64) {
            STAGE(kt + 1, (kt + 1) & 1)
        }
        const int cur = kt & 1;

        // ---- QK^T: S(32x64) ----
        floatx4 sacc[2][4] = {};
        #pragma unroll
        for (int n = 0; n < 4; ++n) {
            const int row = n * 16 + fr;
            #pragma unroll
            for (int ks = 0; ks < 2; ++ks) {
                const bf16x8 bk = *reinterpret_cast<const bf16x8*>(
                    (const char*)&Ks[cur][0] + row * 128 + ((ks * 64 + hi * 16) ^ ((row & 7) << 4)));
                #pragma unroll
                for (int m = 0; m < 2; ++m)
                    sacc[m][n] = __builtin_amdgcn_mfma_f32_16x16x32_bf16(aq[m][ks], bk, sacc[m][n], 0, 0, 0);
            }
        }

        // ---- key padding mask ----
        #pragma unroll
        for (int n = 0; n < 4; ++n) {
            if (mrow_g[kt * 64 + n * 16 + fr] == 0) {
                #pragma unroll
                for (int m = 0; m < 2; ++m)
                    #pragma unroll
                    for (int r = 0; r < 4; ++r) sacc[m][n][r] = -3.4028234663852886e38f;
            }
        }

        // ---- online softmax (rows = hi*4+r within 16-block m; cols across lane&15) ----
        #pragma unroll
        for (int m = 0; m < 2; ++m) {
            #pragma unroll
            for (int r = 0; r < 4; ++r) {
                float mx = fmaxf(fmaxf(sacc[m][0][r], sacc[m][1][r]),
                                 fmaxf(sacc[m][2][r], sacc[m][3][r]));
                mx = fmaxf(mx, __shfl_xor(mx, 1));
                mx = fmaxf(mx, __shfl_xor(mx, 2));
                mx = fmaxf(mx, __shfl_xor(mx, 4));
                mx = fmaxf(mx, __shfl_xor(mx, 8));
                const float mnew = fmaxf(mrow[m][r], mx);
                const float f = __expf(mrow[m][r] - mnew);
                mrow[m][r] = mnew;
                float rs = 0.0f;
                #pragma unroll
                for (int n = 0; n < 4; ++n) {
                    const float p = __expf(sacc[m][n][r] - mnew);
                    sacc[m][n][r] = p;
                    rs += p;
                }
                rs += __shfl_xor(rs, 1);
                rs += __shfl_xor(rs, 2);
                rs += __shfl_xor(rs, 4);
                rs += __shfl_xor(rs, 8);
                lrow[m][r] = lrow[m][r] * f + rs;
                #pragma unroll
                for (int nd = 0; nd < 4; ++nd)
                    #pragma unroll
                    for (int rr = 0; rr < 1; ++rr)  // scale this row's o elems
                        oacc[m][nd][r] *= f;
            }
        }

        // ---- P -> bf16, fragment-major LDS (each 16B chunk = one reader lane's frag) ----
        unsigned short* pb = &Ps[w][0];
        #pragma unroll
        for (int m = 0; m < 2; ++m) {
            #pragma unroll
            for (int n = 0; n < 4; ++n) {
                const int frag = m * 2 + (n >> 1);
                const int lp   = ((n & 1) * 2 + (lo >> 3)) * 16 + hi * 4;
                #pragma unroll
                for (int r = 0; r < 4; ++r)
                    pb[(frag * 64 + lp + r) * 8 + (lo & 7)] = f2bf(sacc[m][n][r]);
            }
        }

        // ---- PV: O(32x64) += P(32x64) @ V(64x64) ----
        #pragma unroll
        for (int ks = 0; ks < 2; ++ks) {
            bf16x8 ap[2];
            #pragma unroll
            for (int qb = 0; qb < 2; ++qb)
                ap[qb] = *reinterpret_cast<const bf16x8*>(&Ps[w][((qb * 2 + ks) * 64 + lane) * 8]);
            #pragma unroll
            for (int nd = 0; nd < 4; ++nd) {
                const int row = nd * 16 + fr;
                const bf16x8 bv = *reinterpret_cast<const bf16x8*>(
                    (const char*)&Vs[cur][0] + row * 128 + ((ks * 64 + hi * 16) ^ ((row & 7) << 4)));
                #pragma unroll
                for (int qb = 0; qb < 2; ++qb)
                    oacc[qb][nd] = __builtin_amdgcn_mfma_f32_16x16x32_bf16(ap[qb], bv, oacc[qb][nd], 0, 0, 0);
            }
        }
    }

    // ---- epilogue: ctx bf16 [b][s][h*64+d] ----
    #pragma unroll
    for (int qb = 0; qb < 2; ++qb) {
        #pragma unroll
        for (int r = 0; r < 4; ++r) {
            const int qrow = q0 + qb * 16 + hi * 4 + r;
            const float inv = 1.0f / lrow[qb][r];
            #pragma unroll
            for (int nd = 0; nd < 4; ++nd) {
                const int d = nd * 16 + lo;
                ctxb[((size_t)b * S_LEN + qrow) * DMODEL + h * HD + d] = f2bf(oacc[qb][nd][r] * inv);
            }
        }
    }
    #undef STAGE
}

extern "C" void kernel_launch(void* const* d_in, const int* in_sizes, int n_in,
                              void* d_out, int out_size, void* d_ws, size_t ws_size,
                              hipStream_t stream) {
    const float* x    = (const float*)d_in[0];
    const int*   mask = (const int*)d_in[1];
    const float* wq = (const float*)d_in[2];
    const float* bq = (const float*)d_in[3];
    const float* wk = (const float*)d_in[4];
    const float* bk = (const float*)d_in[5];
    const float* wv = (const float*)d_in[6];
    const float* bv = (const float*)d_in[7];
    const float* wo = (const float*)d_in[8];
    const float* bo = (const float*)d_in[9];
    float* out = (float*)d_out;

    const size_t QKV = (size_t)M_TOK * DMODEL;   // 8388608
    float* qb = (float*)d_ws;                    // fp32 q heads (dead after rope)
    float* kb = qb + QKV;                        // fp32 k heads (dead after rope)
    unsigned short* qbf = (unsigned short*)(kb + QKV);
    unsigned short* kbf = qbf + QKV;
    unsigned short* vtb = kbf + QKV;             // bf16 V^T [bh][d][s]
    unsigned short* xb  = vtb + QKV;
    unsigned short* wtq = xb + QKV;
    unsigned short* wtk = wtq + (size_t)DMODEL * DMODEL;
    unsigned short* wtv = wtk + (size_t)DMODEL * DMODEL;
    unsigned short* wto = wtv + (size_t)DMODEL * DMODEL;
    float* cs = (float*)(wto + (size_t)DMODEL * DMODEL);
    float* sn = cs + (size_t)S_LEN * 32;
    unsigned short* ctxb = (unsigned short*)qb;  // alias: qb fp32 dead by attn time

    rope_table_kernel<<<S_LEN * 32 / 256, 256, 0, stream>>>(cs, sn);
    convert_x_kernel<<<QKV / (256 * 4), 256, 0, stream>>>(x, xb);

    dim3 tgrid(DMODEL / 32, DMODEL / 32);
    convert_transpose_w<<<tgrid, 256, 0, stream>>>(wq, wtq);
    convert_transpose_w<<<tgrid, 256, 0, stream>>>(wk, wtk);
    convert_transpose_w<<<tgrid, 256, 0, stream>>>(wv, wtv);
    convert_transpose_w<<<tgrid, 256, 0, stream>>>(wo, wto);

    dim3 ggrid(DMODEL / 128, M_TOK / 128);   // (8, 64)
    gemm_mfma<0><<<ggrid, 256, 0, stream>>>(xb, wtq, bq, nullptr, qb);
    gemm_mfma<0><<<ggrid, 256, 0, stream>>>(xb, wtk, bk, nullptr, kb);
    gemm_mfma<2><<<ggrid, 256, 0, stream>>>(xb, wtv, bv, nullptr, (float*)vtb);

    rope_apply_bf16<<<BATCH * NH * S_LEN * 32 / 256, 256, 0, stream>>>(qb, kb, cs, sn, qbf, kbf);

    dim3 agrid(S_LEN / 128, BATCH * NH);     // (16, 64)
    attn_mfma_kernel<<<agrid, 256, 0, stream>>>(qbf, kbf, vtb, mask, ctxb);

    gemm_mfma<1><<<ggrid, 256, 0, stream>>>(ctxb, wto, bo, mask, out);
}

// Round 4
// 354.607 us; speedup vs baseline: 3.5804x; 1.4563x over previous
//
#include <hip/hip_runtime.h>
#include <math.h>

#define S_LEN  2048
#define NH     16
#define HD     64
#define DMODEL 1024
#define BATCH  4
#define M_TOK  (BATCH * S_LEN)   // 8192

typedef __bf16 bf16x8 __attribute__((ext_vector_type(8)));
typedef float  floatx4 __attribute__((ext_vector_type(4)));
typedef float  floatx16 __attribute__((ext_vector_type(16)));

typedef __attribute__((address_space(1))) const void cg_void;
typedef __attribute__((address_space(3))) void lds_void;

__device__ __forceinline__ void gload16(const void* g, void* l) {
    __builtin_amdgcn_global_load_lds((cg_void*)g, (lds_void*)l, 16, 0, 0);
}

__device__ __forceinline__ unsigned short f2bf(float f) {   // RNE f32->bf16
    unsigned int u = __builtin_bit_cast(unsigned int, f);
    u = (u + 0x7FFF + ((u >> 16) & 1)) >> 16;
    return (unsigned short)u;
}

__device__ __forceinline__ unsigned cvtpk(float lo, float hi) {  // [bf16(lo) | bf16(hi)<<16]
    unsigned r;
    asm volatile("v_cvt_pk_bf16_f32 %0, %1, %2" : "=v"(r) : "v"(lo), "v"(hi));
    return r;
}

// (a,b) -> a' = [a.lo32lanes | b.lo32lanes], b' = [a.hi32lanes | b.hi32lanes]
__device__ __forceinline__ void swap32(unsigned &a, unsigned &b) {
    asm volatile("v_permlane32_swap_b32 %0, %1" : "+v"(a), "+v"(b));
}

// ---------------- RoPE cos/sin table: [S_LEN][32] each ----------------
__global__ void rope_table_kernel(float* __restrict__ cs, float* __restrict__ sn) {
    int idx = blockIdx.x * 256 + threadIdx.x;    // 65536
    int j = idx & 31;
    int s = idx >> 5;
    double invf = pow(10000.0, -(double)j / 32.0);
    double a = (double)s * invf;
    cs[idx] = (float)cos(a);
    sn[idx] = (float)sin(a);
}

// ---------------- fp32 -> bf16 convert of x ----------------
__global__ void convert_x_kernel(const float* __restrict__ x, unsigned short* __restrict__ xb) {
    int idx = blockIdx.x * 256 + threadIdx.x;
    float4 a = *reinterpret_cast<const float4*>(&x[(size_t)idx * 4]);
    ushort4 o;
    o.x = f2bf(a.x); o.y = f2bf(a.y); o.z = f2bf(a.z); o.w = f2bf(a.w);
    *reinterpret_cast<ushort4*>(&xb[(size_t)idx * 4]) = o;
}

// ---------------- W [K][N] fp32  ->  Wt [N][K] bf16 ----------------
__global__ void convert_transpose_w(const float* __restrict__ w, unsigned short* __restrict__ wt) {
    __shared__ float tile[32][33];
    int tx  = threadIdx.x & 31;
    int ty8 = threadIdx.x >> 5;
    int n0 = blockIdx.x * 32;
    int k0 = blockIdx.y * 32;
    #pragma unroll
    for (int i = 0; i < 4; ++i)
        tile[ty8 + i * 8][tx] = w[(size_t)(k0 + ty8 + i * 8) * DMODEL + n0 + tx];
    __syncthreads();
    #pragma unroll
    for (int i = 0; i < 4; ++i)
        wt[(size_t)(n0 + ty8 + i * 8) * DMODEL + k0 + tx] = f2bf(tile[tx][ty8 + i * 8]);
}

// ---------------- fused QKV GEMM + RoPE epilogue ----------------
// A: xb [8192][1024] bf16.  Bt: wq|wk|wv transposed stack [3072][1024] bf16.
// sect = col0>>10: 0 -> qbf bf16 [bh][s][d] (pre-scaled 0.125, RoPE'd)
//                  1 -> kbf bf16 [bh][s][d] (RoPE'd)
//                  2 -> vtb bf16 [bh][d][s]
__global__ __launch_bounds__(256)
void gemm_qkv(const unsigned short* __restrict__ A, const unsigned short* __restrict__ Bt,
              const float* __restrict__ bq, const float* __restrict__ bk,
              const float* __restrict__ bv,
              const float* __restrict__ cs, const float* __restrict__ sn,
              unsigned short* __restrict__ qbf, unsigned short* __restrict__ kbf,
              unsigned short* __restrict__ vtb)
{
    constexpr int K = DMODEL;
    __shared__ unsigned short As[2][128 * 32];
    __shared__ unsigned short Bs[2][128 * 32];

    const int tid  = threadIdx.x;
    const int lane = tid & 63;
    const int w    = tid >> 6;
    const int wm   = w >> 1;
    const int wn   = w & 1;
    const int row0 = blockIdx.y * 128;
    const int col0 = blockIdx.x * 128;    // 0..2944

    const int sr  = lane >> 2;
    const int sk8 = (lane & 3) * 8;
    const int fr  = lane & 15;
    const int fk  = (lane >> 4) * 8;

    floatx4 acc[4][4] = {};

    #pragma unroll
    for (int t = 0; t < 2; ++t) {
        const int chunk = w * 32 + t * 16;
        gload16(A  + (size_t)(row0 + chunk + sr) * K + sk8, &As[0][chunk * 32]);
        gload16(Bt + (size_t)(col0 + chunk + sr) * K + sk8, &Bs[0][chunk * 32]);
    }

    for (int kt = 0; kt < K / 32; ++kt) {
        __syncthreads();
        if (kt + 1 < K / 32) {
            const int nb = (kt + 1) & 1;
            const int k0 = (kt + 1) * 32;
            #pragma unroll
            for (int t = 0; t < 2; ++t) {
                const int chunk = w * 32 + t * 16;
                gload16(A  + (size_t)(row0 + chunk + sr) * K + k0 + sk8, &As[nb][chunk * 32]);
                gload16(Bt + (size_t)(col0 + chunk + sr) * K + k0 + sk8, &Bs[nb][chunk * 32]);
            }
        }
        const int cur = kt & 1;
        bf16x8 av[4], bv4[4];
        #pragma unroll
        for (int m = 0; m < 4; ++m)
            av[m] = *reinterpret_cast<const bf16x8*>(&As[cur][(wm * 64 + m * 16 + fr) * 32 + fk]);
        #pragma unroll
        for (int n = 0; n < 4; ++n)
            bv4[n] = *reinterpret_cast<const bf16x8*>(&Bs[cur][(wn * 64 + n * 16 + fr) * 32 + fk]);
        #pragma unroll
        for (int m = 0; m < 4; ++m)
            #pragma unroll
            for (int n = 0; n < 4; ++n)
                acc[m][n] = __builtin_amdgcn_mfma_f32_16x16x32_bf16(av[m], bv4[n], acc[m][n], 0, 0, 0);
    }

    const int rbase = lane >> 4;
    const int sect  = col0 >> 10;        // uniform per block
    const int c0    = col0 & 1023;

    if (sect == 2) {
        #pragma unroll
        for (int m = 0; m < 4; ++m)
            #pragma unroll
            for (int n = 0; n < 4; ++n) {
                const int c  = c0 + wn * 64 + n * 16 + fr;
                const int hh = c >> 6, d = c & 63;
                const int mr0 = row0 + wm * 64 + m * 16 + rbase * 4;
                const int bb = mr0 >> 11, ss = mr0 & (S_LEN - 1);
                const float bc = bv[c];
                ushort4 pk4;
                pk4.x = f2bf(acc[m][n][0] + bc);
                pk4.y = f2bf(acc[m][n][1] + bc);
                pk4.z = f2bf(acc[m][n][2] + bc);
                pk4.w = f2bf(acc[m][n][3] + bc);
                *reinterpret_cast<ushort4*>(
                    &vtb[((size_t)(bb * NH + hh) * HD + d) * S_LEN + ss]) = pk4;
            }
    } else {
        unsigned short* outp = sect ? kbf : qbf;
        const float* bias = sect ? bk : bq;
        const float sc = sect ? 1.0f : 0.125f;
        #pragma unroll
        for (int m = 0; m < 4; ++m)
            #pragma unroll
            for (int n = 0; n < 2; ++n) {       // (d, d+32) pair lives in (n, n+2)
                const int c  = c0 + wn * 64 + n * 16 + fr;
                const int hh = c >> 6, d = c & 63;      // d < 32
                const float b1 = bias[c], b2 = bias[c + 32];
                #pragma unroll
                for (int r = 0; r < 4; ++r) {
                    const int mr = row0 + wm * 64 + m * 16 + rbase * 4 + r;
                    const int bb = mr >> 11, ss = mr & (S_LEN - 1);
                    const float v1 = acc[m][n][r] + b1;
                    const float v2 = acc[m][n + 2][r] + b2;
                    const float co = cs[ss * 32 + d];
                    const float si = sn[ss * 32 + d];
                    const size_t base = ((size_t)(bb * NH + hh) * S_LEN + ss) * HD + d;
                    outp[base]      = f2bf((v1 * co - v2 * si) * sc);
                    outp[base + 32] = f2bf((v2 * co + v1 * si) * sc);
                }
            }
    }
}

// ---------------- swapped-QK^T MFMA flash attention (32x32x16, in-register softmax) ----------------
// grid (64 heads, 16 qblocks) -> a head's q-blocks share an XCD (bid%8 = head%8).
// 4 waves x 32 q-rows; lane owns ONE q row (q = q0 + lane&31).
__global__ __launch_bounds__(256)
void attn_mfma2(const unsigned short* __restrict__ qbf,
                const unsigned short* __restrict__ kbf,
                const unsigned short* __restrict__ vtb,
                const int* __restrict__ mask,
                unsigned short* __restrict__ ctxb)
{
    __shared__ unsigned short Ks[2][64 * 64];   // [key][d], xor-swizzled via source
    __shared__ unsigned short Vs[2][64 * 64];   // [d][key], xor-swizzled via source
    __shared__ float biasP[2048];               // mask bias, permuted to C-fragment order

    const int tid  = threadIdx.x;
    const int lane = tid & 63;
    const int w    = tid >> 6;
    const int bh   = blockIdx.x;
    const int b    = bh >> 4;
    const int h    = bh & 15;
    const int q0   = blockIdx.y * 128 + w * 32;
    const size_t hb = (size_t)bh * S_LEN * HD;
    const int* mrow_g = mask + b * S_LEN;

    const int lo5 = lane & 31;
    const int hi5 = lane >> 5;
    const int srow   = lane >> 3;                // 0..7
    const int schunk = (lane & 7) ^ srow;        // pre-swizzled source chunk

    // biasP[kt*64 + hi*32 + kb*16 + reg] = bias for key(kt,kb,hi,reg)
    for (int i = tid; i < 2048; i += 256) {
        const int kt = i >> 6, rem = i & 63;
        const int hig = rem >> 5, kb = (rem >> 4) & 1, reg = rem & 15;
        const int key = kt * 64 + kb * 32 + hig * 4 + (reg & 3) + ((reg >> 2) << 3);
        biasP[i] = mrow_g[key] ? 0.0f : -3.0e38f;
    }

    // Q as MFMA-B fragments: lane holds Q[q=lo5][d = 16ks + 8hi5 + j]
    bf16x8 qf[4];
    #pragma unroll
    for (int ks = 0; ks < 4; ++ks)
        qf[ks] = *reinterpret_cast<const bf16x8*>(
            &qbf[hb + (size_t)(q0 + lo5) * HD + ks * 16 + hi5 * 8]);

    floatx16 oacc[2];
    #pragma unroll
    for (int v = 0; v < 2; ++v)
        #pragma unroll
        for (int i = 0; i < 16; ++i) oacc[v][i] = 0.0f;
    float mrow = -3.0e38f, lrow = 0.0f;

    #define STAGE(KT, BUF)                                                                  \
        _Pragma("unroll")                                                                   \
        for (int t = 0; t < 2; ++t) {                                                       \
            const int r0 = w * 16 + t * 8;                                                  \
            gload16(kbf + hb + (size_t)((KT) * 64 + r0 + srow) * HD + schunk * 8,           \
                    &Ks[BUF][r0 * 64]);                                                     \
            gload16(vtb + ((size_t)bh * HD + r0 + srow) * S_LEN + (KT) * 64 + schunk * 8,   \
                    &Vs[BUF][r0 * 64]);                                                     \
        }

    STAGE(0, 0)

    for (int kt = 0; kt < S_LEN / 64; ++kt) {
        __syncthreads();
        if (kt + 1 < S_LEN / 64) { STAGE(kt + 1, (kt + 1) & 1) }
        const int cur = kt & 1;

        // S^T = K.Q^T + maskbias ; C-init from broadcast LDS reads
        floatx16 sacc[2];
        #pragma unroll
        for (int kb = 0; kb < 2; ++kb) {
            const float4* bp = reinterpret_cast<const float4*>(&biasP[kt * 64 + hi5 * 32 + kb * 16]);
            #pragma unroll
            for (int t = 0; t < 4; ++t) {
                const float4 b4 = bp[t];
                sacc[kb][t * 4 + 0] = b4.x; sacc[kb][t * 4 + 1] = b4.y;
                sacc[kb][t * 4 + 2] = b4.z; sacc[kb][t * 4 + 3] = b4.w;
            }
        }

        __builtin_amdgcn_s_setprio(1);
        #pragma unroll
        for (int kb = 0; kb < 2; ++kb) {
            #pragma unroll
            for (int ks = 0; ks < 4; ++ks) {
                const bf16x8 ak = *reinterpret_cast<const bf16x8*>(
                    (const char*)&Ks[cur][0] + (kb * 32 + lo5) * 128 +
                    ((ks * 32 + hi5 * 16) ^ ((lo5 & 7) << 4)));
                sacc[kb] = __builtin_amdgcn_mfma_f32_32x32x16_bf16(ak, qf[ks], sacc[kb], 0, 0, 0);
            }
        }
        __builtin_amdgcn_s_setprio(0);

        // ---- in-register online softmax: lane holds 32 of 64 keys, partner = lane^32 ----
        float pmax = sacc[0][0];
        #pragma unroll
        for (int i = 1; i < 16; ++i) pmax = fmaxf(pmax, sacc[0][i]);
        #pragma unroll
        for (int i = 0; i < 16; ++i) pmax = fmaxf(pmax, sacc[1][i]);
        pmax = fmaxf(pmax, __shfl_xor(pmax, 32));
        const float mnew = fmaxf(mrow, pmax);
        const float fscale = __expf(mrow - mnew);
        mrow = mnew;
        float rs = 0.0f;
        #pragma unroll
        for (int kb = 0; kb < 2; ++kb)
            #pragma unroll
            for (int i = 0; i < 16; ++i) {
                const float p = __expf(sacc[kb][i] - mnew);
                sacc[kb][i] = p;
                rs += p;
            }
        rs += __shfl_xor(rs, 32);
        lrow = lrow * fscale + rs;
        #pragma unroll
        for (int v = 0; v < 2; ++v)
            #pragma unroll
            for (int i = 0; i < 16; ++i) oacc[v][i] *= fscale;

        // ---- P -> bf16 PV B-fragments entirely in-register (T12) ----
        // lane owns keys 8g + 4*hi5 + {0..3}, g=0..7 (g = 4kb+s)
        unsigned U0[8], U1[8];
        #pragma unroll
        for (int kb = 0; kb < 2; ++kb)
            #pragma unroll
            for (int s = 0; s < 4; ++s) {
                U0[kb * 4 + s] = cvtpk(sacc[kb][4 * s + 0], sacc[kb][4 * s + 1]);
                U1[kb * 4 + s] = cvtpk(sacc[kb][4 * s + 2], sacc[kb][4 * s + 3]);
            }
        union PF { unsigned u[4]; bf16x8 v; };
        PF pf[4];
        #pragma unroll
        for (int ks = 0; ks < 4; ++ks) {
            unsigned a0 = U0[2 * ks], b0 = U0[2 * ks + 1];
            swap32(a0, b0);
            unsigned a1 = U1[2 * ks], b1 = U1[2 * ks + 1];
            swap32(a1, b1);
            pf[ks].u[0] = a0; pf[ks].u[1] = a1;   // keys 16ks + 8hi5 + {0..3}
            pf[ks].u[2] = b0; pf[ks].u[3] = b1;   // keys 16ks + 8hi5 + {4..7}
        }

        // ---- O^T += V^T . P^T ----
        __builtin_amdgcn_s_setprio(1);
        #pragma unroll
        for (int vb = 0; vb < 2; ++vb) {
            #pragma unroll
            for (int ks = 0; ks < 4; ++ks) {
                const bf16x8 av = *reinterpret_cast<const bf16x8*>(
                    (const char*)&Vs[cur][0] + (vb * 32 + lo5) * 128 +
                    ((ks * 32 + hi5 * 16) ^ ((lo5 & 7) << 4)));
                oacc[vb] = __builtin_amdgcn_mfma_f32_32x32x16_bf16(av, pf[ks].v, oacc[vb], 0, 0, 0);
            }
        }
        __builtin_amdgcn_s_setprio(0);
    }

    // ---- epilogue: lane writes its q-row, d = 32vb + 8s + 4hi5 + t ----
    const float inv = 1.0f / lrow;
    unsigned short* dst = &ctxb[((size_t)b * S_LEN + q0 + lo5) * DMODEL + h * HD];
    #pragma unroll
    for (int vb = 0; vb < 2; ++vb)
        #pragma unroll
        for (int s = 0; s < 4; ++s) {
            const int d0 = vb * 32 + s * 8 + hi5 * 4;
            ushort4 o4;
            o4.x = f2bf(oacc[vb][4 * s + 0] * inv);
            o4.y = f2bf(oacc[vb][4 * s + 1] * inv);
            o4.z = f2bf(oacc[vb][4 * s + 2] * inv);
            o4.w = f2bf(oacc[vb][4 * s + 3] * inv);
            *reinterpret_cast<ushort4*>(&dst[d0]) = o4;
        }
    #undef STAGE
}

// ---------------- output projection: out = (ctxb @ wto^T + bo) * mask ----------------
__global__ __launch_bounds__(256)
void gemm_out(const unsigned short* __restrict__ A, const unsigned short* __restrict__ Bt,
              const float* __restrict__ bias, const int* __restrict__ mask,
              float* __restrict__ C)
{
    constexpr int K = DMODEL;
    __shared__ unsigned short As[2][128 * 32];
    __shared__ unsigned short Bs[2][128 * 32];

    const int tid  = threadIdx.x;
    const int lane = tid & 63;
    const int w    = tid >> 6;
    const int wm   = w >> 1;
    const int wn   = w & 1;
    const int row0 = blockIdx.y * 128;
    const int col0 = blockIdx.x * 128;

    const int sr  = lane >> 2;
    const int sk8 = (lane & 3) * 8;
    const int fr  = lane & 15;
    const int fk  = (lane >> 4) * 8;

    floatx4 acc[4][4] = {};

    #pragma unroll
    for (int t = 0; t < 2; ++t) {
        const int chunk = w * 32 + t * 16;
        gload16(A  + (size_t)(row0 + chunk + sr) * K + sk8, &As[0][chunk * 32]);
        gload16(Bt + (size_t)(col0 + chunk + sr) * K + sk8, &Bs[0][chunk * 32]);
    }

    for (int kt = 0; kt < K / 32; ++kt) {
        __syncthreads();
        if (kt + 1 < K / 32) {
            const int nb = (kt + 1) & 1;
            const int k0 = (kt + 1) * 32;
            #pragma unroll
            for (int t = 0; t < 2; ++t) {
                const int chunk = w * 32 + t * 16;
                gload16(A  + (size_t)(row0 + chunk + sr) * K + k0 + sk8, &As[nb][chunk * 32]);
                gload16(Bt + (size_t)(col0 + chunk + sr) * K + k0 + sk8, &Bs[nb][chunk * 32]);
            }
        }
        const int cur = kt & 1;
        bf16x8 av[4], bv4[4];
        #pragma unroll
        for (int m = 0; m < 4; ++m)
            av[m] = *reinterpret_cast<const bf16x8*>(&As[cur][(wm * 64 + m * 16 + fr) * 32 + fk]);
        #pragma unroll
        for (int n = 0; n < 4; ++n)
            bv4[n] = *reinterpret_cast<const bf16x8*>(&Bs[cur][(wn * 64 + n * 16 + fr) * 32 + fk]);
        #pragma unroll
        for (int m = 0; m < 4; ++m)
            #pragma unroll
            for (int n = 0; n < 4; ++n)
                acc[m][n] = __builtin_amdgcn_mfma_f32_16x16x32_bf16(av[m], bv4[n], acc[m][n], 0, 0, 0);
    }

    const int rbase = lane >> 4;
    #pragma unroll
    for (int m = 0; m < 4; ++m)
        #pragma unroll
        for (int n = 0; n < 4; ++n) {
            const int c = col0 + wn * 64 + n * 16 + fr;
            const float bc = bias[c];
            #pragma unroll
            for (int r = 0; r < 4; ++r) {
                const int mr = row0 + wm * 64 + m * 16 + rbase * 4 + r;
                C[(size_t)mr * DMODEL + c] = mask[mr] ? (acc[m][n][r] + bc) : 0.0f;
            }
        }
}

extern "C" void kernel_launch(void* const* d_in, const int* in_sizes, int n_in,
                              void* d_out, int out_size, void* d_ws, size_t ws_size,
                              hipStream_t stream) {
    const float* x    = (const float*)d_in[0];
    const int*   mask = (const int*)d_in[1];
    const float* wq = (const float*)d_in[2];
    const float* bq = (const float*)d_in[3];
    const float* wk = (const float*)d_in[4];
    const float* bk = (const float*)d_in[5];
    const float* wv = (const float*)d_in[6];
    const float* bv = (const float*)d_in[7];
    const float* wo = (const float*)d_in[8];
    const float* bo = (const float*)d_in[9];
    float* out = (float*)d_out;

    const size_t QKV = (size_t)M_TOK * DMODEL;     // 8388608
    const size_t WSZ = (size_t)DMODEL * DMODEL;    // 1048576
    unsigned short* xb     = (unsigned short*)d_ws;
    unsigned short* wstack = xb + QKV;             // wq^T | wk^T | wv^T contiguous
    unsigned short* wto    = wstack + 3 * WSZ;
    unsigned short* qbf    = wto + WSZ;
    unsigned short* kbf    = qbf + QKV;
    unsigned short* vtb    = kbf + QKV;
    unsigned short* ctxb   = vtb + QKV;
    float* cs = (float*)(ctxb + QKV);
    float* sn = cs + (size_t)S_LEN * 32;
    // total ~89 MB

    rope_table_kernel<<<S_LEN * 32 / 256, 256, 0, stream>>>(cs, sn);
    convert_x_kernel<<<QKV / (256 * 4), 256, 0, stream>>>(x, xb);

    dim3 tgrid(DMODEL / 32, DMODEL / 32);
    convert_transpose_w<<<tgrid, 256, 0, stream>>>(wq, wstack);
    convert_transpose_w<<<tgrid, 256, 0, stream>>>(wk, wstack + WSZ);
    convert_transpose_w<<<tgrid, 256, 0, stream>>>(wv, wstack + 2 * WSZ);
    convert_transpose_w<<<tgrid, 256, 0, stream>>>(wo, wto);

    dim3 qkvgrid(3 * DMODEL / 128, M_TOK / 128);   // (24, 64)
    gemm_qkv<<<qkvgrid, 256, 0, stream>>>(xb, wstack, bq, bk, bv, cs, sn, qbf, kbf, vtb);

    dim3 agrid(BATCH * NH, S_LEN / 128);           // (64 heads, 16 qblocks)
    attn_mfma2<<<agrid, 256, 0, stream>>>(qbf, kbf, vtb, mask, ctxb);

    dim3 ogrid(DMODEL / 128, M_TOK / 128);         // (8, 64)
    gemm_out<<<ogrid, 256, 0, stream>>>(ctxb, wto, bo, mask, out);
}

// Round 5
// 341.473 us; speedup vs baseline: 3.7182x; 1.0385x over previous
//
#include <hip/hip_runtime.h>
#include <math.h>

#define S_LEN  2048
#define NH     16
#define HD     64
#define DMODEL 1024
#define BATCH  4
#define M_TOK  (BATCH * S_LEN)   // 8192

typedef __bf16 bf16x8 __attribute__((ext_vector_type(8)));
typedef float  floatx4 __attribute__((ext_vector_type(4)));
typedef float  floatx16 __attribute__((ext_vector_type(16)));

typedef __attribute__((address_space(1))) const void cg_void;
typedef __attribute__((address_space(3))) void lds_void;

#if __has_builtin(__builtin_amdgcn_exp2f)
#define EXP2(x) __builtin_amdgcn_exp2f(x)
#else
#define EXP2(x) exp2f(x)
#endif

__device__ __forceinline__ void gload16(const void* g, void* l) {
    __builtin_amdgcn_global_load_lds((cg_void*)g, (lds_void*)l, 16, 0, 0);
}

__device__ __forceinline__ unsigned short f2bf(float f) {   // RNE f32->bf16
    unsigned int u = __builtin_bit_cast(unsigned int, f);
    u = (u + 0x7FFF + ((u >> 16) & 1)) >> 16;
    return (unsigned short)u;
}

__device__ __forceinline__ unsigned cvtpk(float lo, float hi) {  // [bf16(lo) | bf16(hi)<<16]
    unsigned r;
    asm volatile("v_cvt_pk_bf16_f32 %0, %1, %2" : "=v"(r) : "v"(lo), "v"(hi));
    return r;
}

// (a,b) -> a' = [a.lo32lanes | b.lo32lanes], b' = [a.hi32lanes | b.hi32lanes]
__device__ __forceinline__ void swap32(unsigned &a, unsigned &b) {
    asm volatile("v_permlane32_swap_b32 %0, %1" : "+v"(a), "+v"(b));
}

__device__ __forceinline__ float max3f(float a, float b, float c) {
    float r;
    asm("v_max3_f32 %0, %1, %2, %3" : "=v"(r) : "v"(a), "v"(b), "v"(c));
    return r;
}

// ---------------- fused prep kernel ----------------
// sections by blockIdx.x:
//  [0, 8192)        : x fp32 -> bf16            (1024 elems/block)
//  [8192, 12288)    : 4 weight transposes fp32[K][N] -> bf16[N][K]
//  [12288, 12544)   : RoPE cos/sin table [S_LEN][32]
//  [12544]          : mask bias (fragment order) + per-tile validity flags
__global__ __launch_bounds__(256)
void prep_kernel(const float* __restrict__ x,
                 const float* __restrict__ wq, const float* __restrict__ wk,
                 const float* __restrict__ wv, const float* __restrict__ wo,
                 const int* __restrict__ mask,
                 unsigned short* __restrict__ xb, unsigned short* __restrict__ wstack,
                 unsigned short* __restrict__ wto,
                 float* __restrict__ cs, float* __restrict__ sn,
                 float* __restrict__ biasG, int* __restrict__ flags)
{
    __shared__ float tile[32][33];
    const int blk = blockIdx.x;
    const int tid = threadIdx.x;
    constexpr size_t WSZ = (size_t)DMODEL * DMODEL;

    if (blk < 8192) {                       // ---- convert x ----
        const int idx = blk * 256 + tid;
        float4 a = *reinterpret_cast<const float4*>(&x[(size_t)idx * 4]);
        ushort4 o;
        o.x = f2bf(a.x); o.y = f2bf(a.y); o.z = f2bf(a.z); o.w = f2bf(a.w);
        *reinterpret_cast<ushort4*>(&xb[(size_t)idx * 4]) = o;
    } else if (blk < 12288) {               // ---- weight transposes ----
        const int rel = blk - 8192;
        const int mat = rel >> 10;
        const float* w = (mat == 0) ? wq : (mat == 1) ? wk : (mat == 2) ? wv : wo;
        unsigned short* wt = (mat < 3) ? (wstack + (size_t)mat * WSZ) : wto;
        const int rel10 = rel & 1023;
        const int n0 = (rel10 & 31) * 32;
        const int k0 = (rel10 >> 5) * 32;
        const int tx  = tid & 31;
        const int ty8 = tid >> 5;
        #pragma unroll
        for (int i = 0; i < 4; ++i)
            tile[ty8 + i * 8][tx] = w[(size_t)(k0 + ty8 + i * 8) * DMODEL + n0 + tx];
        __syncthreads();
        #pragma unroll
        for (int i = 0; i < 4; ++i)
            wt[(size_t)(n0 + ty8 + i * 8) * DMODEL + k0 + tx] = f2bf(tile[tx][ty8 + i * 8]);
    } else if (blk < 12544) {               // ---- RoPE table ----
        const int idx = (blk - 12288) * 256 + tid;
        const int j = idx & 31;
        const int s = idx >> 5;
        double invf = pow(10000.0, -(double)j / 32.0);
        double a = (double)s * invf;
        cs[idx] = (float)cos(a);
        sn[idx] = (float)sin(a);
    } else {                                // ---- mask bias + flags ----
        for (int i = tid; i < BATCH * S_LEN; i += 256) {
            const int b = i >> 11, r = i & 2047;
            const int kt = r >> 6, rem = r & 63;
            const int hig = rem >> 5, kbb = (rem >> 4) & 1, reg = rem & 15;
            const int key = kt * 64 + kbb * 32 + hig * 4 + (reg & 3) + ((reg >> 2) << 3);
            biasG[i] = mask[b * S_LEN + key] ? 0.0f : -3.0e38f;
        }
        for (int i = tid; i < BATCH * 32; i += 256) {
            const int b = i >> 5, kt = i & 31;
            int ok = 1;
            for (int j = 0; j < 64; ++j) ok &= (mask[b * S_LEN + kt * 64 + j] != 0);
            flags[i] = ok;
        }
    }
}

// ---------------- fused QKV GEMM + RoPE epilogue ----------------
// A: xb [8192][1024] bf16.  Bt: wq|wk|wv transposed stack [3072][1024] bf16.
// sect: 0 -> qbf [bh][s][d] (pre-scaled 0.125*log2e, RoPE'd)
//       1 -> kbf [bh][s][d] (RoPE'd)
//       2 -> vtb [bh][d][s]
__global__ __launch_bounds__(256)
void gemm_qkv(const unsigned short* __restrict__ A, const unsigned short* __restrict__ Bt,
              const float* __restrict__ bq, const float* __restrict__ bk,
              const float* __restrict__ bv,
              const float* __restrict__ cs, const float* __restrict__ sn,
              unsigned short* __restrict__ qbf, unsigned short* __restrict__ kbf,
              unsigned short* __restrict__ vtb)
{
    constexpr int K = DMODEL;
    __shared__ unsigned short As[2][128 * 32];
    __shared__ unsigned short Bs[2][128 * 32];

    const int tid  = threadIdx.x;
    const int lane = tid & 63;
    const int w    = tid >> 6;
    const int wm   = w >> 1;
    const int wn   = w & 1;

    // XCD-bijective swizzle: nwg = 24*64 = 1536, 1536%8==0
    {
    }
    const int gx   = gridDim.x;                 // 24
    int lin = blockIdx.y * gx + blockIdx.x;
    const int cpx = (gx * gridDim.y) >> 3;
    lin = (lin & 7) * cpx + (lin >> 3);
    const int row0 = (lin / gx) * 128;
    const int col0 = (lin % gx) * 128;          // 0..2944

    const int sr  = lane >> 2;
    const int sk8 = (lane & 3) * 8;
    const int fr  = lane & 15;
    const int fk  = (lane >> 4) * 8;

    floatx4 acc[4][4] = {};

    #pragma unroll
    for (int t = 0; t < 2; ++t) {
        const int chunk = w * 32 + t * 16;
        gload16(A  + (size_t)(row0 + chunk + sr) * K + sk8, &As[0][chunk * 32]);
        gload16(Bt + (size_t)(col0 + chunk + sr) * K + sk8, &Bs[0][chunk * 32]);
    }

    for (int kt = 0; kt < K / 32; ++kt) {
        __syncthreads();
        if (kt + 1 < K / 32) {
            const int nb = (kt + 1) & 1;
            const int k0 = (kt + 1) * 32;
            #pragma unroll
            for (int t = 0; t < 2; ++t) {
                const int chunk = w * 32 + t * 16;
                gload16(A  + (size_t)(row0 + chunk + sr) * K + k0 + sk8, &As[nb][chunk * 32]);
                gload16(Bt + (size_t)(col0 + chunk + sr) * K + k0 + sk8, &Bs[nb][chunk * 32]);
            }
        }
        const int cur = kt & 1;
        bf16x8 av[4], bv4[4];
        #pragma unroll
        for (int m = 0; m < 4; ++m)
            av[m] = *reinterpret_cast<const bf16x8*>(&As[cur][(wm * 64 + m * 16 + fr) * 32 + fk]);
        #pragma unroll
        for (int n = 0; n < 4; ++n)
            bv4[n] = *reinterpret_cast<const bf16x8*>(&Bs[cur][(wn * 64 + n * 16 + fr) * 32 + fk]);
        #pragma unroll
        for (int m = 0; m < 4; ++m)
            #pragma unroll
            for (int n = 0; n < 4; ++n)
                acc[m][n] = __builtin_amdgcn_mfma_f32_16x16x32_bf16(av[m], bv4[n], acc[m][n], 0, 0, 0);
    }

    const int rbase = lane >> 4;
    const int sect  = col0 >> 10;        // uniform per block
    const int c0    = col0 & 1023;

    if (sect == 2) {
        #pragma unroll
        for (int m = 0; m < 4; ++m)
            #pragma unroll
            for (int n = 0; n < 4; ++n) {
                const int c  = c0 + wn * 64 + n * 16 + fr;
                const int hh = c >> 6, d = c & 63;
                const int mr0 = row0 + wm * 64 + m * 16 + rbase * 4;
                const int bb = mr0 >> 11, ss = mr0 & (S_LEN - 1);
                const float bc = bv[c];
                ushort4 pk4;
                pk4.x = f2bf(acc[m][n][0] + bc);
                pk4.y = f2bf(acc[m][n][1] + bc);
                pk4.z = f2bf(acc[m][n][2] + bc);
                pk4.w = f2bf(acc[m][n][3] + bc);
                *reinterpret_cast<ushort4*>(
                    &vtb[((size_t)(bb * NH + hh) * HD + d) * S_LEN + ss]) = pk4;
            }
    } else {
        unsigned short* outp = sect ? kbf : qbf;
        const float* bias = sect ? bk : bq;
        const float sc = sect ? 1.0f : 0.125f * 1.44269504088896f;  // fold log2e into Q
        #pragma unroll
        for (int m = 0; m < 4; ++m)
            #pragma unroll
            for (int n = 0; n < 2; ++n) {       // (d, d+32) pair lives in (n, n+2)
                const int c  = c0 + wn * 64 + n * 16 + fr;
                const int hh = c >> 6, d = c & 63;      // d < 32
                const float b1 = bias[c], b2 = bias[c + 32];
                #pragma unroll
                for (int r = 0; r < 4; ++r) {
                    const int mr = row0 + wm * 64 + m * 16 + rbase * 4 + r;
                    const int bb = mr >> 11, ss = mr & (S_LEN - 1);
                    const float v1 = acc[m][n][r] + b1;
                    const float v2 = acc[m][n + 2][r] + b2;
                    const float co = cs[ss * 32 + d];
                    const float si = sn[ss * 32 + d];
                    const size_t base = ((size_t)(bb * NH + hh) * S_LEN + ss) * HD + d;
                    outp[base]      = f2bf((v1 * co - v2 * si) * sc);
                    outp[base + 32] = f2bf((v2 * co + v1 * si) * sc);
                }
            }
    }
}

// ---------------- swapped-QK^T MFMA flash attention (log2-domain softmax, defer-max) ----------------
// grid (64 heads, 16 qblocks): lin%8 = head%8 -> a head's q-blocks share an XCD.
// 4 waves x 32 q-rows; lane owns ONE q row (q = q0 + lane&31).
__global__ __launch_bounds__(256)
void attn_mfma2(const unsigned short* __restrict__ qbf,
                const unsigned short* __restrict__ kbf,
                const unsigned short* __restrict__ vtb,
                const float* __restrict__ biasG,
                const int* __restrict__ flags,
                unsigned short* __restrict__ ctxb)
{
    __shared__ unsigned short Ks[2][64 * 64];   // [key][d], xor-swizzled via source
    __shared__ unsigned short Vs[2][64 * 64];   // [d][key], xor-swizzled via source

    const int tid  = threadIdx.x;
    const int lane = tid & 63;
    const int w    = tid >> 6;
    const int bh   = blockIdx.x;
    const int b    = bh >> 4;
    const int h    = bh & 15;
    const int q0   = blockIdx.y * 128 + w * 32;
    const size_t hb = (size_t)bh * S_LEN * HD;

    const int lo5 = lane & 31;
    const int hi5 = lane >> 5;
    const int srow   = lane >> 3;                // 0..7
    const int schunk = (lane & 7) ^ srow;        // pre-swizzled source chunk

    // Q as MFMA-B fragments: lane holds Q[q=lo5][d = 16ks + 8hi5 + j]
    bf16x8 qf[4];
    #pragma unroll
    for (int ks = 0; ks < 4; ++ks)
        qf[ks] = *reinterpret_cast<const bf16x8*>(
            &qbf[hb + (size_t)(q0 + lo5) * HD + ks * 16 + hi5 * 8]);

    floatx16 oacc[2];
    #pragma unroll
    for (int v = 0; v < 2; ++v)
        #pragma unroll
        for (int i = 0; i < 16; ++i) oacc[v][i] = 0.0f;
    float mrow = -3.0e38f, lrow = 0.0f;

    #define STAGE(KT, BUF)                                                                  \
        _Pragma("unroll")                                                                   \
        for (int t = 0; t < 2; ++t) {                                                       \
            const int r0 = w * 16 + t * 8;                                                  \
            gload16(kbf + hb + (size_t)((KT) * 64 + r0 + srow) * HD + schunk * 8,           \
                    &Ks[BUF][r0 * 64]);                                                     \
            gload16(vtb + ((size_t)bh * HD + r0 + srow) * S_LEN + (KT) * 64 + schunk * 8,   \
                    &Vs[BUF][r0 * 64]);                                                     \
        }

    STAGE(0, 0)

    for (int kt = 0; kt < S_LEN / 64; ++kt) {
        __syncthreads();
        if (kt + 1 < S_LEN / 64) { STAGE(kt + 1, (kt + 1) & 1) }
        const int cur = kt & 1;

        // ---- S^T = K.Q^T (+ mask bias C-init when tile has invalid keys) ----
        floatx16 sacc[2];
        if (flags[b * 32 + kt]) {
            #pragma unroll
            for (int kb = 0; kb < 2; ++kb)
                #pragma unroll
                for (int i = 0; i < 16; ++i) sacc[kb][i] = 0.0f;
        } else {
            const float4* bp = reinterpret_cast<const float4*>(
                &biasG[(size_t)(b * 32 + kt) * 64 + hi5 * 32]);
            #pragma unroll
            for (int kb = 0; kb < 2; ++kb)
                #pragma unroll
                for (int t = 0; t < 4; ++t) {
                    const float4 b4 = bp[kb * 4 + t];
                    sacc[kb][t * 4 + 0] = b4.x; sacc[kb][t * 4 + 1] = b4.y;
                    sacc[kb][t * 4 + 2] = b4.z; sacc[kb][t * 4 + 3] = b4.w;
                }
        }

        __builtin_amdgcn_s_setprio(1);
        #pragma unroll
        for (int kb = 0; kb < 2; ++kb) {
            #pragma unroll
            for (int ks = 0; ks < 4; ++ks) {
                const bf16x8 ak = *reinterpret_cast<const bf16x8*>(
                    (const char*)&Ks[cur][0] + (kb * 32 + lo5) * 128 +
                    ((ks * 32 + hi5 * 16) ^ ((lo5 & 7) << 4)));
                sacc[kb] = __builtin_amdgcn_mfma_f32_32x32x16_bf16(ak, qf[ks], sacc[kb], 0, 0, 0);
            }
        }
        __builtin_amdgcn_s_setprio(0);

        // ---- log2-domain online softmax with defer-max (T13, THR=8) ----
        // max over 32 values via v_max3 tree (16 ops)
        float r0 = max3f(sacc[0][0],  sacc[0][1],  sacc[0][2]);
        float r1 = max3f(sacc[0][3],  sacc[0][4],  sacc[0][5]);
        float r2 = max3f(sacc[0][6],  sacc[0][7],  sacc[0][8]);
        float r3 = max3f(sacc[0][9],  sacc[0][10], sacc[0][11]);
        float r4 = max3f(sacc[0][12], sacc[0][13], sacc[0][14]);
        float r5 = max3f(sacc[1][0],  sacc[1][1],  sacc[1][2]);
        float r6 = max3f(sacc[1][3],  sacc[1][4],  sacc[1][5]);
        float r7 = max3f(sacc[1][6],  sacc[1][7],  sacc[1][8]);
        float r8 = max3f(sacc[1][9],  sacc[1][10], sacc[1][11]);
        float r9 = max3f(sacc[1][12], sacc[1][13], sacc[1][14]);
        float s1 = max3f(r0, r1, r2);
        float s2 = max3f(r3, r4, r5);
        float s3 = max3f(r6, r7, r8);
        float s4 = max3f(r9, sacc[0][15], sacc[1][15]);
        float pmax = fmaxf(max3f(s1, s2, s3), s4);
        pmax = fmaxf(pmax, __shfl_xor(pmax, 32));

        if (!__all(pmax <= mrow + 8.0f)) {     // rescale path (rare)
            const float mnew = fmaxf(mrow, pmax);
            const float fscale = EXP2(mrow - mnew);
            mrow = mnew;
            lrow *= fscale;
            #pragma unroll
            for (int v = 0; v < 2; ++v)
                #pragma unroll
                for (int i = 0; i < 16; ++i) oacc[v][i] *= fscale;
        }

        float rs0 = 0.0f, rs1 = 0.0f, rs2 = 0.0f, rs3 = 0.0f;
        #pragma unroll
        for (int kb = 0; kb < 2; ++kb)
            #pragma unroll
            for (int i = 0; i < 16; i += 4) {
                float p0 = EXP2(sacc[kb][i + 0] - mrow);
                float p1 = EXP2(sacc[kb][i + 1] - mrow);
                float p2 = EXP2(sacc[kb][i + 2] - mrow);
                float p3 = EXP2(sacc[kb][i + 3] - mrow);
                sacc[kb][i + 0] = p0; sacc[kb][i + 1] = p1;
                sacc[kb][i + 2] = p2; sacc[kb][i + 3] = p3;
                rs0 += p0; rs1 += p1; rs2 += p2; rs3 += p3;
            }
        float rs = (rs0 + rs1) + (rs2 + rs3);
        rs += __shfl_xor(rs, 32);
        lrow += rs;

        // ---- P -> bf16 PV B-fragments entirely in-register (T12) ----
        unsigned U0[8], U1[8];
        #pragma unroll
        for (int kb = 0; kb < 2; ++kb)
            #pragma unroll
            for (int s = 0; s < 4; ++s) {
                U0[kb * 4 + s] = cvtpk(sacc[kb][4 * s + 0], sacc[kb][4 * s + 1]);
                U1[kb * 4 + s] = cvtpk(sacc[kb][4 * s + 2], sacc[kb][4 * s + 3]);
            }
        union PF { unsigned u[4]; bf16x8 v; };
        PF pf[4];
        #pragma unroll
        for (int ks = 0; ks < 4; ++ks) {
            unsigned a0 = U0[2 * ks], b0 = U0[2 * ks + 1];
            swap32(a0, b0);
            unsigned a1 = U1[2 * ks], b1 = U1[2 * ks + 1];
            swap32(a1, b1);
            pf[ks].u[0] = a0; pf[ks].u[1] = a1;
            pf[ks].u[2] = b0; pf[ks].u[3] = b1;
        }

        // ---- O^T += V^T . P^T ----
        __builtin_amdgcn_s_setprio(1);
        #pragma unroll
        for (int vb = 0; vb < 2; ++vb) {
            #pragma unroll
            for (int ks = 0; ks < 4; ++ks) {
                const bf16x8 av = *reinterpret_cast<const bf16x8*>(
                    (const char*)&Vs[cur][0] + (vb * 32 + lo5) * 128 +
                    ((ks * 32 + hi5 * 16) ^ ((lo5 & 7) << 4)));
                oacc[vb] = __builtin_amdgcn_mfma_f32_32x32x16_bf16(av, pf[ks].v, oacc[vb], 0, 0, 0);
            }
        }
        __builtin_amdgcn_s_setprio(0);
    }

    // ---- epilogue: lane writes its q-row, d = 32vb + 8s + 4hi5 + t ----
    const float inv = 1.0f / lrow;
    unsigned short* dst = &ctxb[((size_t)b * S_LEN + q0 + lo5) * DMODEL + h * HD];
    #pragma unroll
    for (int vb = 0; vb < 2; ++vb)
        #pragma unroll
        for (int s = 0; s < 4; ++s) {
            const int d0 = vb * 32 + s * 8 + hi5 * 4;
            ushort4 o4;
            o4.x = f2bf(oacc[vb][4 * s + 0] * inv);
            o4.y = f2bf(oacc[vb][4 * s + 1] * inv);
            o4.z = f2bf(oacc[vb][4 * s + 2] * inv);
            o4.w = f2bf(oacc[vb][4 * s + 3] * inv);
            *reinterpret_cast<ushort4*>(&dst[d0]) = o4;
        }
    #undef STAGE
}

// ---------------- output projection: out = (ctxb @ wto^T + bo) * mask ----------------
__global__ __launch_bounds__(256)
void gemm_out(const unsigned short* __restrict__ A, const unsigned short* __restrict__ Bt,
              const float* __restrict__ bias, const int* __restrict__ mask,
              float* __restrict__ C)
{
    constexpr int K = DMODEL;
    __shared__ unsigned short As[2][128 * 32];
    __shared__ unsigned short Bs[2][128 * 32];

    const int tid  = threadIdx.x;
    const int lane = tid & 63;
    const int w    = tid >> 6;
    const int wm   = w >> 1;
    const int wn   = w & 1;

    // XCD-bijective swizzle: nwg = 8*64 = 512, 512%8==0
    const int gx   = gridDim.x;                 // 8
    int lin = blockIdx.y * gx + blockIdx.x;
    const int cpx = (gx * gridDim.y) >> 3;
    lin = (lin & 7) * cpx + (lin >> 3);
    const int row0 = (lin >> 3) * 128;          // lin / 8
    const int col0 = (lin & 7) * 128;

    const int sr  = lane >> 2;
    const int sk8 = (lane & 3) * 8;
    const int fr  = lane & 15;
    const int fk  = (lane >> 4) * 8;

    floatx4 acc[4][4] = {};

    #pragma unroll
    for (int t = 0; t < 2; ++t) {
        const int chunk = w * 32 + t * 16;
        gload16(A  + (size_t)(row0 + chunk + sr) * K + sk8, &As[0][chunk * 32]);
        gload16(Bt + (size_t)(col0 + chunk + sr) * K + sk8, &Bs[0][chunk * 32]);
    }

    for (int kt = 0; kt < K / 32; ++kt) {
        __syncthreads();
        if (kt + 1 < K / 32) {
            const int nb = (kt + 1) & 1;
            const int k0 = (kt + 1) * 32;
            #pragma unroll
            for (int t = 0; t < 2; ++t) {
                const int chunk = w * 32 + t * 16;
                gload16(A  + (size_t)(row0 + chunk + sr) * K + k0 + sk8, &As[nb][chunk * 32]);
                gload16(Bt + (size_t)(col0 + chunk + sr) * K + k0 + sk8, &Bs[nb][chunk * 32]);
            }
        }
        const int cur = kt & 1;
        bf16x8 av[4], bv4[4];
        #pragma unroll
        for (int m = 0; m < 4; ++m)
            av[m] = *reinterpret_cast<const bf16x8*>(&As[cur][(wm * 64 + m * 16 + fr) * 32 + fk]);
        #pragma unroll
        for (int n = 0; n < 4; ++n)
            bv4[n] = *reinterpret_cast<const bf16x8*>(&Bs[cur][(wn * 64 + n * 16 + fr) * 32 + fk]);
        #pragma unroll
        for (int m = 0; m < 4; ++m)
            #pragma unroll
            for (int n = 0; n < 4; ++n)
                acc[m][n] = __builtin_amdgcn_mfma_f32_16x16x32_bf16(av[m], bv4[n], acc[m][n], 0, 0, 0);
    }

    const int rbase = lane >> 4;
    #pragma unroll
    for (int m = 0; m < 4; ++m)
        #pragma unroll
        for (int n = 0; n < 4; ++n) {
            const int c = col0 + wn * 64 + n * 16 + fr;
            const float bc = bias[c];
            #pragma unroll
            for (int r = 0; r < 4; ++r) {
                const int mr = row0 + wm * 64 + m * 16 + rbase * 4 + r;
                C[(size_t)mr * DMODEL + c] = mask[mr] ? (acc[m][n][r] + bc) : 0.0f;
            }
        }
}

extern "C" void kernel_launch(void* const* d_in, const int* in_sizes, int n_in,
                              void* d_out, int out_size, void* d_ws, size_t ws_size,
                              hipStream_t stream) {
    const float* x    = (const float*)d_in[0];
    const int*   mask = (const int*)d_in[1];
    const float* wq = (const float*)d_in[2];
    const float* bq = (const float*)d_in[3];
    const float* wk = (const float*)d_in[4];
    const float* bk = (const float*)d_in[5];
    const float* wv = (const float*)d_in[6];
    const float* bv = (const float*)d_in[7];
    const float* wo = (const float*)d_in[8];
    const float* bo = (const float*)d_in[9];
    float* out = (float*)d_out;

    const size_t QKV = (size_t)M_TOK * DMODEL;     // 8388608
    const size_t WSZ = (size_t)DMODEL * DMODEL;    // 1048576
    unsigned short* xb     = (unsigned short*)d_ws;
    unsigned short* wstack = xb + QKV;             // wq^T | wk^T | wv^T contiguous
    unsigned short* wto    = wstack + 3 * WSZ;
    unsigned short* qbf    = wto + WSZ;
    unsigned short* kbf    = qbf + QKV;
    unsigned short* vtb    = kbf + QKV;
    unsigned short* ctxb   = vtb + QKV;
    float* cs    = (float*)(ctxb + QKV);
    float* sn    = cs + (size_t)S_LEN * 32;
    float* biasG = sn + (size_t)S_LEN * 32;        // [4][2048] fragment-ordered
    int*   flags = (int*)(biasG + (size_t)BATCH * S_LEN);   // [4][32]
    // total ~90 MB

    prep_kernel<<<12545, 256, 0, stream>>>(x, wq, wk, wv, wo, mask,
                                           xb, wstack, wto, cs, sn, biasG, flags);

    dim3 qkvgrid(3 * DMODEL / 128, M_TOK / 128);   // (24, 64)
    gemm_qkv<<<qkvgrid, 256, 0, stream>>>(xb, wstack, bq, bk, bv, cs, sn, qbf, kbf, vtb);

    dim3 agrid(BATCH * NH, S_LEN / 128);           // (64 heads, 16 qblocks)
    attn_mfma2<<<agrid, 256, 0, stream>>>(qbf, kbf, vtb, biasG, flags, ctxb);

    dim3 ogrid(DMODEL / 128, M_TOK / 128);         // (8, 64)
    gemm_out<<<ogrid, 256, 0, stream>>>(ctxb, wto, bo, mask, out);
}

// Round 6
// 309.760 us; speedup vs baseline: 4.0988x; 1.1024x over previous
//
#include <hip/hip_runtime.h>
#include <math.h>

#define S_LEN  2048
#define NH     16
#define HD     64
#define DMODEL 1024
#define BATCH  4
#define M_TOK  (BATCH * S_LEN)   // 8192

typedef __bf16 bf16x8 __attribute__((ext_vector_type(8)));
typedef float  floatx4 __attribute__((ext_vector_type(4)));
typedef float  floatx16 __attribute__((ext_vector_type(16)));

typedef __attribute__((address_space(1))) const void cg_void;
typedef __attribute__((address_space(3))) void lds_void;

#if __has_builtin(__builtin_amdgcn_exp2f)
#define EXP2(x) __builtin_amdgcn_exp2f(x)
#else
#define EXP2(x) exp2f(x)
#endif

__device__ __forceinline__ void gload16(const void* g, void* l) {
    __builtin_amdgcn_global_load_lds((cg_void*)g, (lds_void*)l, 16, 0, 0);
}

__device__ __forceinline__ unsigned short f2bf(float f) {   // RNE f32->bf16
    unsigned int u = __builtin_bit_cast(unsigned int, f);
    u = (u + 0x7FFF + ((u >> 16) & 1)) >> 16;
    return (unsigned short)u;
}

__device__ __forceinline__ unsigned cvtpk(float lo, float hi) {  // [bf16(lo) | bf16(hi)<<16]
    unsigned r;
    asm volatile("v_cvt_pk_bf16_f32 %0, %1, %2" : "=v"(r) : "v"(lo), "v"(hi));
    return r;
}

// (a,b) -> a' = [a.lo32lanes | b.lo32lanes], b' = [a.hi32lanes | b.hi32lanes]
__device__ __forceinline__ void swap32(unsigned &a, unsigned &b) {
    asm volatile("v_permlane32_swap_b32 %0, %1" : "+v"(a), "+v"(b));
}

__device__ __forceinline__ float max3f(float a, float b, float c) {
    float r;
    asm("v_max3_f32 %0, %1, %2, %3" : "=v"(r) : "v"(a), "v"(b), "v"(c));
    return r;
}

// ---------------- fused prep kernel ----------------
// sections by blockIdx.x:
//  [0, 8192)        : x fp32 -> bf16            (1024 elems/block)
//  [8192, 12288)    : 4 weight transposes fp32[K][N] -> bf16[N][K]
//  [12288, 12544)   : RoPE cos/sin table [S_LEN][32]  (fp32 math)
//  [12544]          : mask bias (fragment order) + per-batch tile-valid bitmask
__global__ __launch_bounds__(256)
void prep_kernel(const float* __restrict__ x,
                 const float* __restrict__ wq, const float* __restrict__ wk,
                 const float* __restrict__ wv, const float* __restrict__ wo,
                 const int* __restrict__ mask,
                 unsigned short* __restrict__ xb, unsigned short* __restrict__ wstack,
                 unsigned short* __restrict__ wto,
                 float* __restrict__ cs, float* __restrict__ sn,
                 float* __restrict__ biasG, unsigned* __restrict__ flagmask)
{
    __shared__ float tile[32][33];
    __shared__ unsigned fm[4];
    const int blk = blockIdx.x;
    const int tid = threadIdx.x;
    constexpr size_t WSZ = (size_t)DMODEL * DMODEL;

    if (blk < 8192) {                       // ---- convert x ----
        const int idx = blk * 256 + tid;
        float4 a = *reinterpret_cast<const float4*>(&x[(size_t)idx * 4]);
        ushort4 o;
        o.x = f2bf(a.x); o.y = f2bf(a.y); o.z = f2bf(a.z); o.w = f2bf(a.w);
        *reinterpret_cast<ushort4*>(&xb[(size_t)idx * 4]) = o;
    } else if (blk < 12288) {               // ---- weight transposes ----
        const int rel = blk - 8192;
        const int mat = rel >> 10;
        const float* w = (mat == 0) ? wq : (mat == 1) ? wk : (mat == 2) ? wv : wo;
        unsigned short* wt = (mat < 3) ? (wstack + (size_t)mat * WSZ) : wto;
        const int rel10 = rel & 1023;
        const int n0 = (rel10 & 31) * 32;
        const int k0 = (rel10 >> 5) * 32;
        const int tx  = tid & 31;
        const int ty8 = tid >> 5;
        #pragma unroll
        for (int i = 0; i < 4; ++i)
            tile[ty8 + i * 8][tx] = w[(size_t)(k0 + ty8 + i * 8) * DMODEL + n0 + tx];
        __syncthreads();
        #pragma unroll
        for (int i = 0; i < 4; ++i)
            wt[(size_t)(n0 + ty8 + i * 8) * DMODEL + k0 + tx] = f2bf(tile[tx][ty8 + i * 8]);
    } else if (blk < 12544) {               // ---- RoPE table (fp32) ----
        const int idx = (blk - 12288) * 256 + tid;
        const int j = idx & 31;
        const int s = idx >> 5;
        // invf = 10000^(-j/32) ; angle error <= ~2e-4 rad << bf16 tolerance
        const float invf = exp2f(-(float)j * (13.287712379549449f / 32.0f));
        const float a = (float)s * invf;
        cs[idx] = cosf(a);
        sn[idx] = sinf(a);
    } else {                                // ---- mask bias + flag bitmask ----
        for (int i = tid; i < BATCH * S_LEN; i += 256) {
            const int b = i >> 11, r = i & 2047;
            const int kt = r >> 6, rem = r & 63;
            const int hig = rem >> 5, kbb = (rem >> 4) & 1, reg = rem & 15;
            const int key = kt * 64 + kbb * 32 + hig * 4 + (reg & 3) + ((reg >> 2) << 3);
            biasG[i] = mask[b * S_LEN + key] ? 0.0f : -3.0e38f;
        }
        if (tid < 4) fm[tid] = 0;
        __syncthreads();
        for (int i = tid; i < BATCH * 32; i += 256) {
            const int b = i >> 5, kt = i & 31;
            int ok = 1;
            for (int j = 0; j < 64; ++j) ok &= (mask[b * S_LEN + kt * 64 + j] != 0);
            if (ok) atomicOr(&fm[b], 1u << kt);
        }
        __syncthreads();
        if (tid < 4) flagmask[tid] = fm[tid];
    }
}

// ---------------- fused QKV GEMM + RoPE epilogue ----------------
// A: xb [8192][1024] bf16.  Bt: wq|wk|wv transposed stack [3072][1024] bf16.
// sect: 0 -> qbf [bh][s][d] (pre-scaled 0.125*log2e, RoPE'd)
//       1 -> kbf [bh][s][d] (RoPE'd)
//       2 -> vtb [bh][d][s]
__global__ __launch_bounds__(256)
void gemm_qkv(const unsigned short* __restrict__ A, const unsigned short* __restrict__ Bt,
              const float* __restrict__ bq, const float* __restrict__ bk,
              const float* __restrict__ bv,
              const float* __restrict__ cs, const float* __restrict__ sn,
              unsigned short* __restrict__ qbf, unsigned short* __restrict__ kbf,
              unsigned short* __restrict__ vtb)
{
    constexpr int K = DMODEL;
    __shared__ unsigned short As[2][128 * 32];
    __shared__ unsigned short Bs[2][128 * 32];

    const int tid  = threadIdx.x;
    const int lane = tid & 63;
    const int w    = tid >> 6;
    const int wm   = w >> 1;
    const int wn   = w & 1;

    // XCD-bijective swizzle: nwg = 24*64 = 1536, 1536%8==0
    const int gx   = gridDim.x;                 // 24
    int lin = blockIdx.y * gx + blockIdx.x;
    const int cpx = (gx * gridDim.y) >> 3;
    lin = (lin & 7) * cpx + (lin >> 3);
    const int row0 = (lin / gx) * 128;
    const int col0 = (lin % gx) * 128;          // 0..2944

    const int sr  = lane >> 2;
    const int sk8 = (lane & 3) * 8;
    const int fr  = lane & 15;
    const int fk  = (lane >> 4) * 8;

    floatx4 acc[4][4] = {};

    #pragma unroll
    for (int t = 0; t < 2; ++t) {
        const int chunk = w * 32 + t * 16;
        gload16(A  + (size_t)(row0 + chunk + sr) * K + sk8, &As[0][chunk * 32]);
        gload16(Bt + (size_t)(col0 + chunk + sr) * K + sk8, &Bs[0][chunk * 32]);
    }

    for (int kt = 0; kt < K / 32; ++kt) {
        __syncthreads();
        if (kt + 1 < K / 32) {
            const int nb = (kt + 1) & 1;
            const int k0 = (kt + 1) * 32;
            #pragma unroll
            for (int t = 0; t < 2; ++t) {
                const int chunk = w * 32 + t * 16;
                gload16(A  + (size_t)(row0 + chunk + sr) * K + k0 + sk8, &As[nb][chunk * 32]);
                gload16(Bt + (size_t)(col0 + chunk + sr) * K + k0 + sk8, &Bs[nb][chunk * 32]);
            }
        }
        const int cur = kt & 1;
        bf16x8 av[4], bv4[4];
        #pragma unroll
        for (int m = 0; m < 4; ++m)
            av[m] = *reinterpret_cast<const bf16x8*>(&As[cur][(wm * 64 + m * 16 + fr) * 32 + fk]);
        #pragma unroll
        for (int n = 0; n < 4; ++n)
            bv4[n] = *reinterpret_cast<const bf16x8*>(&Bs[cur][(wn * 64 + n * 16 + fr) * 32 + fk]);
        #pragma unroll
        for (int m = 0; m < 4; ++m)
            #pragma unroll
            for (int n = 0; n < 4; ++n)
                acc[m][n] = __builtin_amdgcn_mfma_f32_16x16x32_bf16(av[m], bv4[n], acc[m][n], 0, 0, 0);
    }

    const int rbase = lane >> 4;
    const int sect  = col0 >> 10;        // uniform per block
    const int c0    = col0 & 1023;

    if (sect == 2) {
        #pragma unroll
        for (int m = 0; m < 4; ++m)
            #pragma unroll
            for (int n = 0; n < 4; ++n) {
                const int c  = c0 + wn * 64 + n * 16 + fr;
                const int hh = c >> 6, d = c & 63;
                const int mr0 = row0 + wm * 64 + m * 16 + rbase * 4;
                const int bb = mr0 >> 11, ss = mr0 & (S_LEN - 1);
                const float bc = bv[c];
                ushort4 pk4;
                pk4.x = f2bf(acc[m][n][0] + bc);
                pk4.y = f2bf(acc[m][n][1] + bc);
                pk4.z = f2bf(acc[m][n][2] + bc);
                pk4.w = f2bf(acc[m][n][3] + bc);
                *reinterpret_cast<ushort4*>(
                    &vtb[((size_t)(bb * NH + hh) * HD + d) * S_LEN + ss]) = pk4;
            }
    } else {
        unsigned short* outp = sect ? kbf : qbf;
        const float* bias = sect ? bk : bq;
        const float sc = sect ? 1.0f : 0.125f * 1.44269504088896f;  // fold log2e into Q
        #pragma unroll
        for (int m = 0; m < 4; ++m)
            #pragma unroll
            for (int n = 0; n < 2; ++n) {       // (d, d+32) pair lives in (n, n+2)
                const int c  = c0 + wn * 64 + n * 16 + fr;
                const int hh = c >> 6, d = c & 63;      // d < 32
                const float b1 = bias[c], b2 = bias[c + 32];
                #pragma unroll
                for (int r = 0; r < 4; ++r) {
                    const int mr = row0 + wm * 64 + m * 16 + rbase * 4 + r;
                    const int bb = mr >> 11, ss = mr & (S_LEN - 1);
                    const float v1 = acc[m][n][r] + b1;
                    const float v2 = acc[m][n + 2][r] + b2;
                    const float co = cs[ss * 32 + d];
                    const float si = sn[ss * 32 + d];
                    const size_t base = ((size_t)(bb * NH + hh) * S_LEN + ss) * HD + d;
                    outp[base]      = f2bf((v1 * co - v2 * si) * sc);
                    outp[base + 32] = f2bf((v2 * co + v1 * si) * sc);
                }
            }
    }
}

// ---------------- swapped-QK^T MFMA flash attention, deep pipeline ----------------
// 8 waves x 32 q-rows = 256 q-rows/block; 4 LDS buffers, 2-tile-deep prefetch,
// raw s_barrier + counted vmcnt (never 0 in main loop).
__global__ __launch_bounds__(512)
void attn_mfma3(const unsigned short* __restrict__ qbf,
                const unsigned short* __restrict__ kbf,
                const unsigned short* __restrict__ vtb,
                const float* __restrict__ biasG,
                const unsigned* __restrict__ flagmask,
                unsigned short* __restrict__ ctxb)
{
    __shared__ unsigned short Ks[4][64 * 64];   // [key][d], xor-swizzled via source
    __shared__ unsigned short Vs[4][64 * 64];   // [d][key], xor-swizzled via source

    const int tid  = threadIdx.x;
    const int lane = tid & 63;
    const int w    = tid >> 6;                  // 0..7
    const int bh   = blockIdx.x;
    const int b    = bh >> 4;
    const int h    = bh & 15;
    const int q0   = blockIdx.y * 256 + w * 32;
    const size_t hb = (size_t)bh * S_LEN * HD;

    const int lo5 = lane & 31;
    const int hi5 = lane >> 5;
    const int srow   = lane >> 3;                // 0..7
    const int schunk = (lane & 7) ^ srow;        // pre-swizzled source chunk
    const unsigned fl = flagmask[b];

    // Q as MFMA-B fragments: lane holds Q[q=lo5][d = 16ks + 8hi5 + j]
    bf16x8 qf[4];
    #pragma unroll
    for (int ks = 0; ks < 4; ++ks)
        qf[ks] = *reinterpret_cast<const bf16x8*>(
            &qbf[hb + (size_t)(q0 + lo5) * HD + ks * 16 + hi5 * 8]);

    floatx16 oacc[2];
    #pragma unroll
    for (int v = 0; v < 2; ++v)
        #pragma unroll
        for (int i = 0; i < 16; ++i) oacc[v][i] = 0.0f;
    float mrow = -3.0e38f, lrow = 0.0f;

    // per wave: 1 K-gload + 1 V-gload per tile (8 rows each)
    #define STAGE(KT, BUF) do {                                                             \
        const int r0 = w * 8;                                                               \
        gload16(kbf + hb + (size_t)((KT) * 64 + r0 + srow) * HD + schunk * 8,               \
                &Ks[BUF][r0 * 64]);                                                         \
        gload16(vtb + ((size_t)bh * HD + r0 + srow) * S_LEN + (KT) * 64 + schunk * 8,       \
                &Vs[BUF][r0 * 64]);                                                         \
    } while (0)

    auto TILE = [&](int kt, int buf) {
        // ---- S^T = K.Q^T (+ mask bias C-init when tile has invalid keys) ----
        floatx16 sacc[2];
        if ((fl >> kt) & 1u) {
            #pragma unroll
            for (int kb = 0; kb < 2; ++kb)
                #pragma unroll
                for (int i = 0; i < 16; ++i) sacc[kb][i] = 0.0f;
        } else {
            const float4* bp = reinterpret_cast<const float4*>(
                &biasG[(size_t)(b * 32 + kt) * 64 + hi5 * 32]);
            #pragma unroll
            for (int kb = 0; kb < 2; ++kb)
                #pragma unroll
                for (int t = 0; t < 4; ++t) {
                    const float4 b4 = bp[kb * 4 + t];
                    sacc[kb][t * 4 + 0] = b4.x; sacc[kb][t * 4 + 1] = b4.y;
                    sacc[kb][t * 4 + 2] = b4.z; sacc[kb][t * 4 + 3] = b4.w;
                }
        }

        __builtin_amdgcn_s_setprio(1);
        #pragma unroll
        for (int kb = 0; kb < 2; ++kb) {
            #pragma unroll
            for (int ks = 0; ks < 4; ++ks) {
                const bf16x8 ak = *reinterpret_cast<const bf16x8*>(
                    (const char*)&Ks[buf][0] + (kb * 32 + lo5) * 128 +
                    ((ks * 32 + hi5 * 16) ^ ((lo5 & 7) << 4)));
                sacc[kb] = __builtin_amdgcn_mfma_f32_32x32x16_bf16(ak, qf[ks], sacc[kb], 0, 0, 0);
            }
        }
        __builtin_amdgcn_s_setprio(0);

        // ---- log2-domain online softmax with defer-max (THR=8) ----
        float r0 = max3f(sacc[0][0],  sacc[0][1],  sacc[0][2]);
        float r1 = max3f(sacc[0][3],  sacc[0][4],  sacc[0][5]);
        float r2 = max3f(sacc[0][6],  sacc[0][7],  sacc[0][8]);
        float r3 = max3f(sacc[0][9],  sacc[0][10], sacc[0][11]);
        float r4 = max3f(sacc[0][12], sacc[0][13], sacc[0][14]);
        float r5 = max3f(sacc[1][0],  sacc[1][1],  sacc[1][2]);
        float r6 = max3f(sacc[1][3],  sacc[1][4],  sacc[1][5]);
        float r7 = max3f(sacc[1][6],  sacc[1][7],  sacc[1][8]);
        float r8 = max3f(sacc[1][9],  sacc[1][10], sacc[1][11]);
        float r9 = max3f(sacc[1][12], sacc[1][13], sacc[1][14]);
        float s1 = max3f(r0, r1, r2);
        float s2 = max3f(r3, r4, r5);
        float s3 = max3f(r6, r7, r8);
        float s4 = max3f(r9, sacc[0][15], sacc[1][15]);
        float pmax = fmaxf(max3f(s1, s2, s3), s4);
        pmax = fmaxf(pmax, __shfl_xor(pmax, 32));

        if (!__all(pmax <= mrow + 8.0f)) {     // rescale path (rare)
            const float mnew = fmaxf(mrow, pmax);
            const float fscale = EXP2(mrow - mnew);
            mrow = mnew;
            lrow *= fscale;
            #pragma unroll
            for (int v = 0; v < 2; ++v)
                #pragma unroll
                for (int i = 0; i < 16; ++i) oacc[v][i] *= fscale;
        }

        float rs0 = 0.0f, rs1 = 0.0f, rs2 = 0.0f, rs3 = 0.0f;
        #pragma unroll
        for (int kb = 0; kb < 2; ++kb)
            #pragma unroll
            for (int i = 0; i < 16; i += 4) {
                float p0 = EXP2(sacc[kb][i + 0] - mrow);
                float p1 = EXP2(sacc[kb][i + 1] - mrow);
                float p2 = EXP2(sacc[kb][i + 2] - mrow);
                float p3 = EXP2(sacc[kb][i + 3] - mrow);
                sacc[kb][i + 0] = p0; sacc[kb][i + 1] = p1;
                sacc[kb][i + 2] = p2; sacc[kb][i + 3] = p3;
                rs0 += p0; rs1 += p1; rs2 += p2; rs3 += p3;
            }
        float rs = (rs0 + rs1) + (rs2 + rs3);
        rs += __shfl_xor(rs, 32);
        lrow += rs;

        // ---- P -> bf16 PV B-fragments entirely in-register ----
        unsigned U0[8], U1[8];
        #pragma unroll
        for (int kb = 0; kb < 2; ++kb)
            #pragma unroll
            for (int s = 0; s < 4; ++s) {
                U0[kb * 4 + s] = cvtpk(sacc[kb][4 * s + 0], sacc[kb][4 * s + 1]);
                U1[kb * 4 + s] = cvtpk(sacc[kb][4 * s + 2], sacc[kb][4 * s + 3]);
            }
        union PF { unsigned u[4]; bf16x8 v; };
        PF pf[4];
        #pragma unroll
        for (int ks = 0; ks < 4; ++ks) {
            unsigned a0 = U0[2 * ks], b0 = U0[2 * ks + 1];
            swap32(a0, b0);
            unsigned a1 = U1[2 * ks], b1 = U1[2 * ks + 1];
            swap32(a1, b1);
            pf[ks].u[0] = a0; pf[ks].u[1] = a1;
            pf[ks].u[2] = b0; pf[ks].u[3] = b1;
        }

        // ---- O^T += V^T . P^T ----
        __builtin_amdgcn_s_setprio(1);
        #pragma unroll
        for (int vb = 0; vb < 2; ++vb) {
            #pragma unroll
            for (int ks = 0; ks < 4; ++ks) {
                const bf16x8 av = *reinterpret_cast<const bf16x8*>(
                    (const char*)&Vs[buf][0] + (vb * 32 + lo5) * 128 +
                    ((ks * 32 + hi5 * 16) ^ ((lo5 & 7) << 4)));
                oacc[vb] = __builtin_amdgcn_mfma_f32_32x32x16_bf16(av, pf[ks].v, oacc[vb], 0, 0, 0);
            }
        }
        __builtin_amdgcn_s_setprio(0);
    };

    // ---- prologue: 2 tiles in flight ----
    STAGE(0, 0);
    STAGE(1, 1);

    // ---- main loop: counted vmcnt, never 0 (tiles 0..29) ----
    for (int kt = 0; kt < 30; ++kt) {
        STAGE(kt + 2, (kt + 2) & 3);
        asm volatile("s_waitcnt vmcnt(4)" ::: "memory");  // this tile's 2 loads done
        __builtin_amdgcn_s_barrier();
        __builtin_amdgcn_sched_barrier(0);
        TILE(kt, kt & 3);
    }
    // ---- epilogue tiles ----
    asm volatile("s_waitcnt vmcnt(2)" ::: "memory");
    __builtin_amdgcn_s_barrier();
    __builtin_amdgcn_sched_barrier(0);
    TILE(30, 30 & 3);
    asm volatile("s_waitcnt vmcnt(0)" ::: "memory");
    __builtin_amdgcn_s_barrier();
    __builtin_amdgcn_sched_barrier(0);
    TILE(31, 31 & 3);

    // ---- epilogue: lane writes its q-row, d = 32vb + 8s + 4hi5 + t ----
    const float inv = 1.0f / lrow;
    unsigned short* dst = &ctxb[((size_t)b * S_LEN + q0 + lo5) * DMODEL + h * HD];
    #pragma unroll
    for (int vb = 0; vb < 2; ++vb)
        #pragma unroll
        for (int s = 0; s < 4; ++s) {
            const int d0 = vb * 32 + s * 8 + hi5 * 4;
            ushort4 o4;
            o4.x = f2bf(oacc[vb][4 * s + 0] * inv);
            o4.y = f2bf(oacc[vb][4 * s + 1] * inv);
            o4.z = f2bf(oacc[vb][4 * s + 2] * inv);
            o4.w = f2bf(oacc[vb][4 * s + 3] * inv);
            *reinterpret_cast<ushort4*>(&dst[d0]) = o4;
        }
    #undef STAGE
}

// ---------------- output projection: out = (ctxb @ wto^T + bo) * mask ----------------
__global__ __launch_bounds__(256)
void gemm_out(const unsigned short* __restrict__ A, const unsigned short* __restrict__ Bt,
              const float* __restrict__ bias, const int* __restrict__ mask,
              float* __restrict__ C)
{
    constexpr int K = DMODEL;
    __shared__ unsigned short As[2][128 * 32];
    __shared__ unsigned short Bs[2][128 * 32];

    const int tid  = threadIdx.x;
    const int lane = tid & 63;
    const int w    = tid >> 6;
    const int wm   = w >> 1;
    const int wn   = w & 1;

    // XCD-bijective swizzle: nwg = 8*64 = 512, 512%8==0
    const int gx   = gridDim.x;                 // 8
    int lin = blockIdx.y * gx + blockIdx.x;
    const int cpx = (gx * gridDim.y) >> 3;
    lin = (lin & 7) * cpx + (lin >> 3);
    const int row0 = (lin >> 3) * 128;          // lin / 8
    const int col0 = (lin & 7) * 128;

    const int sr  = lane >> 2;
    const int sk8 = (lane & 3) * 8;
    const int fr  = lane & 15;
    const int fk  = (lane >> 4) * 8;

    floatx4 acc[4][4] = {};

    #pragma unroll
    for (int t = 0; t < 2; ++t) {
        const int chunk = w * 32 + t * 16;
        gload16(A  + (size_t)(row0 + chunk + sr) * K + sk8, &As[0][chunk * 32]);
        gload16(Bt + (size_t)(col0 + chunk + sr) * K + sk8, &Bs[0][chunk * 32]);
    }

    for (int kt = 0; kt < K / 32; ++kt) {
        __syncthreads();
        if (kt + 1 < K / 32) {
            const int nb = (kt + 1) & 1;
            const int k0 = (kt + 1) * 32;
            #pragma unroll
            for (int t = 0; t < 2; ++t) {
                const int chunk = w * 32 + t * 16;
                gload16(A  + (size_t)(row0 + chunk + sr) * K + k0 + sk8, &As[nb][chunk * 32]);
                gload16(Bt + (size_t)(col0 + chunk + sr) * K + k0 + sk8, &Bs[nb][chunk * 32]);
            }
        }
        const int cur = kt & 1;
        bf16x8 av[4], bv4[4];
        #pragma unroll
        for (int m = 0; m < 4; ++m)
            av[m] = *reinterpret_cast<const bf16x8*>(&As[cur][(wm * 64 + m * 16 + fr) * 32 + fk]);
        #pragma unroll
        for (int n = 0; n < 4; ++n)
            bv4[n] = *reinterpret_cast<const bf16x8*>(&Bs[cur][(wn * 64 + n * 16 + fr) * 32 + fk]);
        #pragma unroll
        for (int m = 0; m < 4; ++m)
            #pragma unroll
            for (int n = 0; n < 4; ++n)
                acc[m][n] = __builtin_amdgcn_mfma_f32_16x16x32_bf16(av[m], bv4[n], acc[m][n], 0, 0, 0);
    }

    const int rbase = lane >> 4;
    #pragma unroll
    for (int m = 0; m < 4; ++m)
        #pragma unroll
        for (int n = 0; n < 4; ++n) {
            const int c = col0 + wn * 64 + n * 16 + fr;
            const float bc = bias[c];
            #pragma unroll
            for (int r = 0; r < 4; ++r) {
                const int mr = row0 + wm * 64 + m * 16 + rbase * 4 + r;
                C[(size_t)mr * DMODEL + c] = mask[mr] ? (acc[m][n][r] + bc) : 0.0f;
            }
        }
}

extern "C" void kernel_launch(void* const* d_in, const int* in_sizes, int n_in,
                              void* d_out, int out_size, void* d_ws, size_t ws_size,
                              hipStream_t stream) {
    const float* x    = (const float*)d_in[0];
    const int*   mask = (const int*)d_in[1];
    const float* wq = (const float*)d_in[2];
    const float* bq = (const float*)d_in[3];
    const float* wk = (const float*)d_in[4];
    const float* bk = (const float*)d_in[5];
    const float* wv = (const float*)d_in[6];
    const float* bv = (const float*)d_in[7];
    const float* wo = (const float*)d_in[8];
    const float* bo = (const float*)d_in[9];
    float* out = (float*)d_out;

    const size_t QKV = (size_t)M_TOK * DMODEL;     // 8388608
    const size_t WSZ = (size_t)DMODEL * DMODEL;    // 1048576
    unsigned short* xb     = (unsigned short*)d_ws;
    unsigned short* wstack = xb + QKV;             // wq^T | wk^T | wv^T contiguous
    unsigned short* wto    = wstack + 3 * WSZ;
    unsigned short* qbf    = wto + WSZ;
    unsigned short* kbf    = qbf + QKV;
    unsigned short* vtb    = kbf + QKV;
    unsigned short* ctxb   = vtb + QKV;
    float* cs    = (float*)(ctxb + QKV);
    float* sn    = cs + (size_t)S_LEN * 32;
    float* biasG = sn + (size_t)S_LEN * 32;        // [4][2048] fragment-ordered
    unsigned* flagmask = (unsigned*)(biasG + (size_t)BATCH * S_LEN);   // [4] bitmasks
    // total ~90 MB

    prep_kernel<<<12545, 256, 0, stream>>>(x, wq, wk, wv, wo, mask,
                                           xb, wstack, wto, cs, sn, biasG, flagmask);

    dim3 qkvgrid(3 * DMODEL / 128, M_TOK / 128);   // (24, 64)
    gemm_qkv<<<qkvgrid, 256, 0, stream>>>(xb, wstack, bq, bk, bv, cs, sn, qbf, kbf, vtb);

    dim3 agrid(BATCH * NH, S_LEN / 256);           // (64 heads, 8 qblocks)
    attn_mfma3<<<agrid, 512, 0, stream>>>(qbf, kbf, vtb, biasG, flagmask, ctxb);

    dim3 ogrid(DMODEL / 128, M_TOK / 128);         // (8, 64)
    gemm_out<<<ogrid, 256, 0, stream>>>(ctxb, wto, bo, mask, out);
}

// Round 7
// 291.310 us; speedup vs baseline: 4.3584x; 1.0633x over previous
//
#include <hip/hip_runtime.h>
#include <math.h>

#define S_LEN  2048
#define NH     16
#define HD     64
#define DMODEL 1024
#define BATCH  4
#define M_TOK  (BATCH * S_LEN)   // 8192

typedef __bf16 bf16x8 __attribute__((ext_vector_type(8)));
typedef float  floatx4 __attribute__((ext_vector_type(4)));
typedef float  floatx16 __attribute__((ext_vector_type(16)));

typedef __attribute__((address_space(1))) const void cg_void;
typedef __attribute__((address_space(3))) void lds_void;

#if __has_builtin(__builtin_amdgcn_exp2f)
#define EXP2(x) __builtin_amdgcn_exp2f(x)
#else
#define EXP2(x) exp2f(x)
#endif

__device__ __forceinline__ void gload16(const void* g, void* l) {
    __builtin_amdgcn_global_load_lds((cg_void*)g, (lds_void*)l, 16, 0, 0);
}

__device__ __forceinline__ unsigned short f2bf(float f) {   // RNE f32->bf16
    unsigned int u = __builtin_bit_cast(unsigned int, f);
    u = (u + 0x7FFF + ((u >> 16) & 1)) >> 16;
    return (unsigned short)u;
}

__device__ __forceinline__ unsigned cvtpk(float lo, float hi) {  // [bf16(lo) | bf16(hi)<<16]
    unsigned r;
    asm volatile("v_cvt_pk_bf16_f32 %0, %1, %2" : "=v"(r) : "v"(lo), "v"(hi));
    return r;
}

// (a,b) -> a' = [a.lo32lanes | b.lo32lanes], b' = [a.hi32lanes | b.hi32lanes]
__device__ __forceinline__ void swap32(unsigned &a, unsigned &b) {
    asm volatile("v_permlane32_swap_b32 %0, %1" : "+v"(a), "+v"(b));
}

__device__ __forceinline__ float max3f(float a, float b, float c) {
    float r;
    asm("v_max3_f32 %0, %1, %2, %3" : "=v"(r) : "v"(a), "v"(b), "v"(c));
    return r;
}

// ---------------- fused prep kernel ----------------
// sections by blockIdx.x:
//  [0, 8192)        : x fp32 -> bf16            (1024 elems/block)
//  [8192, 12288)    : 4 weight transposes fp32[K][N] -> bf16[N][K]
//  [12288, 12544)   : RoPE cos/sin table [S_LEN][32]  (fp32 math)
//  [12544]          : mask bias (fragment order)
//  [12545]          : per-batch tile-valid bitmask
__global__ __launch_bounds__(256)
void prep_kernel(const float* __restrict__ x,
                 const float* __restrict__ wq, const float* __restrict__ wk,
                 const float* __restrict__ wv, const float* __restrict__ wo,
                 const int* __restrict__ mask,
                 unsigned short* __restrict__ xb, unsigned short* __restrict__ wstack,
                 unsigned short* __restrict__ wto,
                 float* __restrict__ cs, float* __restrict__ sn,
                 float* __restrict__ biasG, unsigned* __restrict__ flagmask)
{
    __shared__ float tile[32][33];
    __shared__ unsigned fm[4];
    const int blk = blockIdx.x;
    const int tid = threadIdx.x;
    constexpr size_t WSZ = (size_t)DMODEL * DMODEL;

    if (blk < 8192) {                       // ---- convert x ----
        const int idx = blk * 256 + tid;
        float4 a = *reinterpret_cast<const float4*>(&x[(size_t)idx * 4]);
        ushort4 o;
        o.x = f2bf(a.x); o.y = f2bf(a.y); o.z = f2bf(a.z); o.w = f2bf(a.w);
        *reinterpret_cast<ushort4*>(&xb[(size_t)idx * 4]) = o;
    } else if (blk < 12288) {               // ---- weight transposes ----
        const int rel = blk - 8192;
        const int mat = rel >> 10;
        const float* w = (mat == 0) ? wq : (mat == 1) ? wk : (mat == 2) ? wv : wo;
        unsigned short* wt = (mat < 3) ? (wstack + (size_t)mat * WSZ) : wto;
        const int rel10 = rel & 1023;
        const int n0 = (rel10 & 31) * 32;
        const int k0 = (rel10 >> 5) * 32;
        const int tx  = tid & 31;
        const int ty8 = tid >> 5;
        #pragma unroll
        for (int i = 0; i < 4; ++i)
            tile[ty8 + i * 8][tx] = w[(size_t)(k0 + ty8 + i * 8) * DMODEL + n0 + tx];
        __syncthreads();
        #pragma unroll
        for (int i = 0; i < 4; ++i)
            wt[(size_t)(n0 + ty8 + i * 8) * DMODEL + k0 + tx] = f2bf(tile[tx][ty8 + i * 8]);
    } else if (blk < 12544) {               // ---- RoPE table (fp32) ----
        const int idx = (blk - 12288) * 256 + tid;
        const int j = idx & 31;
        const int s = idx >> 5;
        const float invf = exp2f(-(float)j * (13.287712379549449f / 32.0f));
        const float a = (float)s * invf;
        cs[idx] = cosf(a);
        sn[idx] = sinf(a);
    } else if (blk == 12544) {              // ---- mask bias ----
        for (int i = tid; i < BATCH * S_LEN; i += 256) {
            const int b = i >> 11, r = i & 2047;
            const int kt = r >> 6, rem = r & 63;
            const int hig = rem >> 5, kbb = (rem >> 4) & 1, reg = rem & 15;
            const int key = kt * 64 + kbb * 32 + hig * 4 + (reg & 3) + ((reg >> 2) << 3);
            biasG[i] = mask[b * S_LEN + key] ? 0.0f : -3.0e38f;
        }
    } else {                                // ---- flag bitmask ----
        if (tid < 4) fm[tid] = 0;
        __syncthreads();
        for (int i = tid; i < BATCH * 32; i += 256) {
            const int b = i >> 5, kt = i & 31;
            int ok = 1;
            for (int j = 0; j < 64; ++j) ok &= (mask[b * S_LEN + kt * 64 + j] != 0);
            if (ok) atomicOr(&fm[b], 1u << kt);
        }
        __syncthreads();
        if (tid < 4) flagmask[tid] = fm[tid];
    }
}

// ---------------- fused QKV GEMM + RoPE epilogue (deep pipeline) ----------------
// A: xb [8192][1024] bf16.  Bt: wq|wk|wv transposed stack [3072][1024] bf16.
// sect: 0 -> qbf [bh][s][pair-interleaved 64] (pre-scaled 0.125*log2e, RoPE'd)
//       1 -> kbf [bh][s][pair-interleaved 64] (RoPE'd)
//       2 -> vtb [bh][d][s]
// q/k row layout: element 2*d + (orig_d>=32), d = orig_d & 31. Same permutation
// for q and k => QK^T dot product unchanged; attn reads rows verbatim.
__global__ __launch_bounds__(256)
void gemm_qkv(const unsigned short* __restrict__ A, const unsigned short* __restrict__ Bt,
              const float* __restrict__ bq, const float* __restrict__ bk,
              const float* __restrict__ bv,
              const float* __restrict__ cs, const float* __restrict__ sn,
              unsigned short* __restrict__ qbf, unsigned short* __restrict__ kbf,
              unsigned short* __restrict__ vtb)
{
    constexpr int K = DMODEL;
    __shared__ unsigned short As[4][128 * 32];   // 32 KB
    __shared__ unsigned short Bs[4][128 * 32];   // 32 KB

    const int tid  = threadIdx.x;
    const int lane = tid & 63;
    const int w    = tid >> 6;
    const int wm   = w >> 1;
    const int wn   = w & 1;

    // XCD-bijective swizzle: nwg = 24*64 = 1536, 1536%8==0
    const int gx   = gridDim.x;                 // 24
    int lin = blockIdx.y * gx + blockIdx.x;
    const int cpx = (gx * gridDim.y) >> 3;
    lin = (lin & 7) * cpx + (lin >> 3);
    const int row0 = (lin / gx) * 128;
    const int col0 = (lin % gx) * 128;          // 0..2944

    const int sr  = lane >> 2;
    const int sk8 = (lane & 3) * 8;
    const int fr  = lane & 15;
    const int fk  = (lane >> 4) * 8;

    floatx4 acc[4][4] = {};

    #define GSTAGE(KT, BUF) do {                                                            \
        const int k0_ = (KT) * 32;                                                          \
        _Pragma("unroll")                                                                   \
        for (int t = 0; t < 2; ++t) {                                                       \
            const int chunk = w * 32 + t * 16;                                              \
            gload16(A  + (size_t)(row0 + chunk + sr) * K + k0_ + sk8, &As[BUF][chunk * 32]);\
            gload16(Bt + (size_t)(col0 + chunk + sr) * K + k0_ + sk8, &Bs[BUF][chunk * 32]);\
        }                                                                                   \
    } while (0)

    auto COMPUTE = [&](int buf) {
        bf16x8 av[4], bv4[4];
        #pragma unroll
        for (int m = 0; m < 4; ++m)
            av[m] = *reinterpret_cast<const bf16x8*>(&As[buf][(wm * 64 + m * 16 + fr) * 32 + fk]);
        #pragma unroll
        for (int n = 0; n < 4; ++n)
            bv4[n] = *reinterpret_cast<const bf16x8*>(&Bs[buf][(wn * 64 + n * 16 + fr) * 32 + fk]);
        __builtin_amdgcn_s_setprio(1);
        #pragma unroll
        for (int m = 0; m < 4; ++m)
            #pragma unroll
            for (int n = 0; n < 4; ++n)
                acc[m][n] = __builtin_amdgcn_mfma_f32_16x16x32_bf16(av[m], bv4[n], acc[m][n], 0, 0, 0);
        __builtin_amdgcn_s_setprio(0);
    };

    GSTAGE(0, 0);
    GSTAGE(1, 1);
    for (int kt = 0; kt < 30; ++kt) {
        GSTAGE(kt + 2, (kt + 2) & 3);
        asm volatile("s_waitcnt vmcnt(8)" ::: "memory");
        __builtin_amdgcn_s_barrier();
        __builtin_amdgcn_sched_barrier(0);
        COMPUTE(kt & 3);
    }
    asm volatile("s_waitcnt vmcnt(4)" ::: "memory");
    __builtin_amdgcn_s_barrier();
    __builtin_amdgcn_sched_barrier(0);
    COMPUTE(2);
    asm volatile("s_waitcnt vmcnt(0)" ::: "memory");
    __builtin_amdgcn_s_barrier();
    __builtin_amdgcn_sched_barrier(0);
    COMPUTE(3);
    #undef GSTAGE

    const int rbase = lane >> 4;
    const int sect  = col0 >> 10;        // uniform per block
    const int c0    = col0 & 1023;

    if (sect == 2) {
        #pragma unroll
        for (int m = 0; m < 4; ++m)
            #pragma unroll
            for (int n = 0; n < 4; ++n) {
                const int c  = c0 + wn * 64 + n * 16 + fr;
                const int hh = c >> 6, d = c & 63;
                const int mr0 = row0 + wm * 64 + m * 16 + rbase * 4;
                const int bb = mr0 >> 11, ss = mr0 & (S_LEN - 1);
                const float bc = bv[c];
                ushort4 pk4;
                pk4.x = f2bf(acc[m][n][0] + bc);
                pk4.y = f2bf(acc[m][n][1] + bc);
                pk4.z = f2bf(acc[m][n][2] + bc);
                pk4.w = f2bf(acc[m][n][3] + bc);
                *reinterpret_cast<ushort4*>(
                    &vtb[((size_t)(bb * NH + hh) * HD + d) * S_LEN + ss]) = pk4;
            }
    } else {
        unsigned short* outp = sect ? kbf : qbf;
        const float* bias = sect ? bk : bq;
        const float sc = sect ? 1.0f : 0.125f * 1.44269504088896f;  // fold log2e into Q
        #pragma unroll
        for (int m = 0; m < 4; ++m)
            #pragma unroll
            for (int n = 0; n < 2; ++n) {       // (d, d+32) pair lives in (n, n+2)
                const int c  = c0 + wn * 64 + n * 16 + fr;
                const int hh = c >> 6, dd = c & 63;     // dd < 32
                const float b1 = bias[c], b2 = bias[c + 32];
                #pragma unroll
                for (int r = 0; r < 4; ++r) {
                    const int mr = row0 + wm * 64 + m * 16 + rbase * 4 + r;
                    const int bb = mr >> 11, ss = mr & (S_LEN - 1);
                    const float v1 = acc[m][n][r] + b1;
                    const float v2 = acc[m][n + 2][r] + b2;
                    const float co = cs[ss * 32 + dd];
                    const float si = sn[ss * 32 + dd];
                    ushort2 st;
                    st.x = f2bf((v1 * co - v2 * si) * sc);
                    st.y = f2bf((v2 * co + v1 * si) * sc);
                    *reinterpret_cast<ushort2*>(
                        &outp[((size_t)(bb * NH + hh) * S_LEN + ss) * HD + 2 * dd]) = st;
                }
            }
    }
}

// ---------------- swapped-QK^T MFMA flash attention, deep pipeline ----------------
// 8 waves x 32 q-rows = 256 q-rows/block; 4 LDS buffers, 2-tile-deep prefetch,
// raw s_barrier + counted vmcnt (never 0 in main loop).
__global__ __launch_bounds__(512)
void attn_mfma3(const unsigned short* __restrict__ qbf,
                const unsigned short* __restrict__ kbf,
                const unsigned short* __restrict__ vtb,
                const float* __restrict__ biasG,
                const unsigned* __restrict__ flagmask,
                unsigned short* __restrict__ ctxb)
{
    __shared__ unsigned short Ks[4][64 * 64];   // [key][d], xor-swizzled via source
    __shared__ unsigned short Vs[4][64 * 64];   // [d][key], xor-swizzled via source

    const int tid  = threadIdx.x;
    const int lane = tid & 63;
    const int w    = tid >> 6;                  // 0..7
    const int bh   = blockIdx.x;
    const int b    = bh >> 4;
    const int h    = bh & 15;
    const int q0   = blockIdx.y * 256 + w * 32;
    const size_t hb = (size_t)bh * S_LEN * HD;

    const int lo5 = lane & 31;
    const int hi5 = lane >> 5;
    const int srow   = lane >> 3;                // 0..7
    const int schunk = (lane & 7) ^ srow;        // pre-swizzled source chunk
    const unsigned fl = flagmask[b];

    // Q as MFMA-B fragments (pair-interleaved layout; same permutation as K)
    bf16x8 qf[4];
    #pragma unroll
    for (int ks = 0; ks < 4; ++ks)
        qf[ks] = *reinterpret_cast<const bf16x8*>(
            &qbf[hb + (size_t)(q0 + lo5) * HD + ks * 16 + hi5 * 8]);

    floatx16 oacc[2];
    #pragma unroll
    for (int v = 0; v < 2; ++v)
        #pragma unroll
        for (int i = 0; i < 16; ++i) oacc[v][i] = 0.0f;
    float mrow = -3.0e38f, lrow = 0.0f;

    // per wave: 1 K-gload + 1 V-gload per tile (8 rows each)
    #define STAGE(KT, BUF) do {                                                             \
        const int r0 = w * 8;                                                               \
        gload16(kbf + hb + (size_t)((KT) * 64 + r0 + srow) * HD + schunk * 8,               \
                &Ks[BUF][r0 * 64]);                                                         \
        gload16(vtb + ((size_t)bh * HD + r0 + srow) * S_LEN + (KT) * 64 + schunk * 8,       \
                &Vs[BUF][r0 * 64]);                                                         \
    } while (0)

    auto TILE = [&](int kt, int buf) {
        // ---- S^T = K.Q^T (+ mask bias C-init when tile has invalid keys) ----
        floatx16 sacc[2];
        if ((fl >> kt) & 1u) {
            #pragma unroll
            for (int kb = 0; kb < 2; ++kb)
                #pragma unroll
                for (int i = 0; i < 16; ++i) sacc[kb][i] = 0.0f;
        } else {
            const float4* bp = reinterpret_cast<const float4*>(
                &biasG[(size_t)(b * 32 + kt) * 64 + hi5 * 32]);
            #pragma unroll
            for (int kb = 0; kb < 2; ++kb)
                #pragma unroll
                for (int t = 0; t < 4; ++t) {
                    const float4 b4 = bp[kb * 4 + t];
                    sacc[kb][t * 4 + 0] = b4.x; sacc[kb][t * 4 + 1] = b4.y;
                    sacc[kb][t * 4 + 2] = b4.z; sacc[kb][t * 4 + 3] = b4.w;
                }
        }

        __builtin_amdgcn_s_setprio(1);
        #pragma unroll
        for (int kb = 0; kb < 2; ++kb) {
            #pragma unroll
            for (int ks = 0; ks < 4; ++ks) {
                const bf16x8 ak = *reinterpret_cast<const bf16x8*>(
                    (const char*)&Ks[buf][0] + (kb * 32 + lo5) * 128 +
                    ((ks * 32 + hi5 * 16) ^ ((lo5 & 7) << 4)));
                sacc[kb] = __builtin_amdgcn_mfma_f32_32x32x16_bf16(ak, qf[ks], sacc[kb], 0, 0, 0);
            }
        }
        __builtin_amdgcn_s_setprio(0);

        // ---- log2-domain online softmax with defer-max (THR=8) ----
        float r0 = max3f(sacc[0][0],  sacc[0][1],  sacc[0][2]);
        float r1 = max3f(sacc[0][3],  sacc[0][4],  sacc[0][5]);
        float r2 = max3f(sacc[0][6],  sacc[0][7],  sacc[0][8]);
        float r3 = max3f(sacc[0][9],  sacc[0][10], sacc[0][11]);
        float r4 = max3f(sacc[0][12], sacc[0][13], sacc[0][14]);
        float r5 = max3f(sacc[1][0],  sacc[1][1],  sacc[1][2]);
        float r6 = max3f(sacc[1][3],  sacc[1][4],  sacc[1][5]);
        float r7 = max3f(sacc[1][6],  sacc[1][7],  sacc[1][8]);
        float r8 = max3f(sacc[1][9],  sacc[1][10], sacc[1][11]);
        float r9 = max3f(sacc[1][12], sacc[1][13], sacc[1][14]);
        float s1 = max3f(r0, r1, r2);
        float s2 = max3f(r3, r4, r5);
        float s3 = max3f(r6, r7, r8);
        float s4 = max3f(r9, sacc[0][15], sacc[1][15]);
        float pmax = fmaxf(max3f(s1, s2, s3), s4);
        pmax = fmaxf(pmax, __shfl_xor(pmax, 32));

        if (!__all(pmax <= mrow + 8.0f)) {     // rescale path (rare)
            const float mnew = fmaxf(mrow, pmax);
            const float fscale = EXP2(mrow - mnew);
            mrow = mnew;
            lrow *= fscale;
            #pragma unroll
            for (int v = 0; v < 2; ++v)
                #pragma unroll
                for (int i = 0; i < 16; ++i) oacc[v][i] *= fscale;
        }

        float rs0 = 0.0f, rs1 = 0.0f, rs2 = 0.0f, rs3 = 0.0f;
        #pragma unroll
        for (int kb = 0; kb < 2; ++kb)
            #pragma unroll
            for (int i = 0; i < 16; i += 4) {
                float p0 = EXP2(sacc[kb][i + 0] - mrow);
                float p1 = EXP2(sacc[kb][i + 1] - mrow);
                float p2 = EXP2(sacc[kb][i + 2] - mrow);
                float p3 = EXP2(sacc[kb][i + 3] - mrow);
                sacc[kb][i + 0] = p0; sacc[kb][i + 1] = p1;
                sacc[kb][i + 2] = p2; sacc[kb][i + 3] = p3;
                rs0 += p0; rs1 += p1; rs2 += p2; rs3 += p3;
            }
        float rs = (rs0 + rs1) + (rs2 + rs3);
        rs += __shfl_xor(rs, 32);
        lrow += rs;

        // ---- P -> bf16 PV B-fragments entirely in-register ----
        unsigned U0[8], U1[8];
        #pragma unroll
        for (int kb = 0; kb < 2; ++kb)
            #pragma unroll
            for (int s = 0; s < 4; ++s) {
                U0[kb * 4 + s] = cvtpk(sacc[kb][4 * s + 0], sacc[kb][4 * s + 1]);
                U1[kb * 4 + s] = cvtpk(sacc[kb][4 * s + 2], sacc[kb][4 * s + 3]);
            }
        union PF { unsigned u[4]; bf16x8 v; };
        PF pf[4];
        #pragma unroll
        for (int ks = 0; ks < 4; ++ks) {
            unsigned a0 = U0[2 * ks], b0 = U0[2 * ks + 1];
            swap32(a0, b0);
            unsigned a1 = U1[2 * ks], b1 = U1[2 * ks + 1];
            swap32(a1, b1);
            pf[ks].u[0] = a0; pf[ks].u[1] = a1;
            pf[ks].u[2] = b0; pf[ks].u[3] = b1;
        }

        // ---- O^T += V^T . P^T ----
        __builtin_amdgcn_s_setprio(1);
        #pragma unroll
        for (int vb = 0; vb < 2; ++vb) {
            #pragma unroll
            for (int ks = 0; ks < 4; ++ks) {
                const bf16x8 av = *reinterpret_cast<const bf16x8*>(
                    (const char*)&Vs[buf][0] + (vb * 32 + lo5) * 128 +
                    ((ks * 32 + hi5 * 16) ^ ((lo5 & 7) << 4)));
                oacc[vb] = __builtin_amdgcn_mfma_f32_32x32x16_bf16(av, pf[ks].v, oacc[vb], 0, 0, 0);
            }
        }
        __builtin_amdgcn_s_setprio(0);
    };

    // ---- prologue: 2 tiles in flight ----
    STAGE(0, 0);
    STAGE(1, 1);

    // ---- main loop: counted vmcnt, never 0 (tiles 0..29) ----
    for (int kt = 0; kt < 30; ++kt) {
        STAGE(kt + 2, (kt + 2) & 3);
        asm volatile("s_waitcnt vmcnt(4)" ::: "memory");  // this tile's 2 loads done
        __builtin_amdgcn_s_barrier();
        __builtin_amdgcn_sched_barrier(0);
        TILE(kt, kt & 3);
    }
    // ---- epilogue tiles ----
    asm volatile("s_waitcnt vmcnt(2)" ::: "memory");
    __builtin_amdgcn_s_barrier();
    __builtin_amdgcn_sched_barrier(0);
    TILE(30, 30 & 3);
    asm volatile("s_waitcnt vmcnt(0)" ::: "memory");
    __builtin_amdgcn_s_barrier();
    __builtin_amdgcn_sched_barrier(0);
    TILE(31, 31 & 3);

    // ---- epilogue: lane writes its q-row, d = 32vb + 8s + 4hi5 + t ----
    const float inv = 1.0f / lrow;
    unsigned short* dst = &ctxb[((size_t)b * S_LEN + q0 + lo5) * DMODEL + h * HD];
    #pragma unroll
    for (int vb = 0; vb < 2; ++vb)
        #pragma unroll
        for (int s = 0; s < 4; ++s) {
            const int d0 = vb * 32 + s * 8 + hi5 * 4;
            ushort4 o4;
            o4.x = f2bf(oacc[vb][4 * s + 0] * inv);
            o4.y = f2bf(oacc[vb][4 * s + 1] * inv);
            o4.z = f2bf(oacc[vb][4 * s + 2] * inv);
            o4.w = f2bf(oacc[vb][4 * s + 3] * inv);
            *reinterpret_cast<ushort4*>(&dst[d0]) = o4;
        }
    #undef STAGE
}

// ---------------- output projection: out = (ctxb @ wto^T + bo) * mask (deep pipeline) ----------------
__global__ __launch_bounds__(256)
void gemm_out(const unsigned short* __restrict__ A, const unsigned short* __restrict__ Bt,
              const float* __restrict__ bias, const int* __restrict__ mask,
              float* __restrict__ C)
{
    constexpr int K = DMODEL;
    __shared__ unsigned short As[4][128 * 32];
    __shared__ unsigned short Bs[4][128 * 32];

    const int tid  = threadIdx.x;
    const int lane = tid & 63;
    const int w    = tid >> 6;
    const int wm   = w >> 1;
    const int wn   = w & 1;

    // XCD-bijective swizzle: nwg = 8*64 = 512, 512%8==0
    const int gx   = gridDim.x;                 // 8
    int lin = blockIdx.y * gx + blockIdx.x;
    const int cpx = (gx * gridDim.y) >> 3;
    lin = (lin & 7) * cpx + (lin >> 3);
    const int row0 = (lin >> 3) * 128;          // lin / 8
    const int col0 = (lin & 7) * 128;

    const int sr  = lane >> 2;
    const int sk8 = (lane & 3) * 8;
    const int fr  = lane & 15;
    const int fk  = (lane >> 4) * 8;

    floatx4 acc[4][4] = {};

    #define GSTAGE(KT, BUF) do {                                                            \
        const int k0_ = (KT) * 32;                                                          \
        _Pragma("unroll")                                                                   \
        for (int t = 0; t < 2; ++t) {                                                       \
            const int chunk = w * 32 + t * 16;                                              \
            gload16(A  + (size_t)(row0 + chunk + sr) * K + k0_ + sk8, &As[BUF][chunk * 32]);\
            gload16(Bt + (size_t)(col0 + chunk + sr) * K + k0_ + sk8, &Bs[BUF][chunk * 32]);\
        }                                                                                   \
    } while (0)

    auto COMPUTE = [&](int buf) {
        bf16x8 av[4], bv4[4];
        #pragma unroll
        for (int m = 0; m < 4; ++m)
            av[m] = *reinterpret_cast<const bf16x8*>(&As[buf][(wm * 64 + m * 16 + fr) * 32 + fk]);
        #pragma unroll
        for (int n = 0; n < 4; ++n)
            bv4[n] = *reinterpret_cast<const bf16x8*>(&Bs[buf][(wn * 64 + n * 16 + fr) * 32 + fk]);
        __builtin_amdgcn_s_setprio(1);
        #pragma unroll
        for (int m = 0; m < 4; ++m)
            #pragma unroll
            for (int n = 0; n < 4; ++n)
                acc[m][n] = __builtin_amdgcn_mfma_f32_16x16x32_bf16(av[m], bv4[n], acc[m][n], 0, 0, 0);
        __builtin_amdgcn_s_setprio(0);
    };

    GSTAGE(0, 0);
    GSTAGE(1, 1);
    for (int kt = 0; kt < 30; ++kt) {
        GSTAGE(kt + 2, (kt + 2) & 3);
        asm volatile("s_waitcnt vmcnt(8)" ::: "memory");
        __builtin_amdgcn_s_barrier();
        __builtin_amdgcn_sched_barrier(0);
        COMPUTE(kt & 3);
    }
    asm volatile("s_waitcnt vmcnt(4)" ::: "memory");
    __builtin_amdgcn_s_barrier();
    __builtin_amdgcn_sched_barrier(0);
    COMPUTE(2);
    asm volatile("s_waitcnt vmcnt(0)" ::: "memory");
    __builtin_amdgcn_s_barrier();
    __builtin_amdgcn_sched_barrier(0);
    COMPUTE(3);
    #undef GSTAGE

    const int rbase = lane >> 4;
    #pragma unroll
    for (int m = 0; m < 4; ++m)
        #pragma unroll
        for (int n = 0; n < 4; ++n) {
            const int c = col0 + wn * 64 + n * 16 + fr;
            const float bc = bias[c];
            #pragma unroll
            for (int r = 0; r < 4; ++r) {
                const int mr = row0 + wm * 64 + m * 16 + rbase * 4 + r;
                C[(size_t)mr * DMODEL + c] = mask[mr] ? (acc[m][n][r] + bc) : 0.0f;
            }
        }
}

extern "C" void kernel_launch(void* const* d_in, const int* in_sizes, int n_in,
                              void* d_out, int out_size, void* d_ws, size_t ws_size,
                              hipStream_t stream) {
    const float* x    = (const float*)d_in[0];
    const int*   mask = (const int*)d_in[1];
    const float* wq = (const float*)d_in[2];
    const float* bq = (const float*)d_in[3];
    const float* wk = (const float*)d_in[4];
    const float* bk = (const float*)d_in[5];
    const float* wv = (const float*)d_in[6];
    const float* bv = (const float*)d_in[7];
    const float* wo = (const float*)d_in[8];
    const float* bo = (const float*)d_in[9];
    float* out = (float*)d_out;

    const size_t QKV = (size_t)M_TOK * DMODEL;     // 8388608
    const size_t WSZ = (size_t)DMODEL * DMODEL;    // 1048576
    unsigned short* xb     = (unsigned short*)d_ws;
    unsigned short* wstack = xb + QKV;             // wq^T | wk^T | wv^T contiguous
    unsigned short* wto    = wstack + 3 * WSZ;
    unsigned short* qbf    = wto + WSZ;
    unsigned short* kbf    = qbf + QKV;
    unsigned short* vtb    = kbf + QKV;
    unsigned short* ctxb   = vtb + QKV;
    float* cs    = (float*)(ctxb + QKV);
    float* sn    = cs + (size_t)S_LEN * 32;
    float* biasG = sn + (size_t)S_LEN * 32;        // [4][2048] fragment-ordered
    unsigned* flagmask = (unsigned*)(biasG + (size_t)BATCH * S_LEN);   // [4] bitmasks
    // total ~90 MB

    prep_kernel<<<12546, 256, 0, stream>>>(x, wq, wk, wv, wo, mask,
                                           xb, wstack, wto, cs, sn, biasG, flagmask);

    dim3 qkvgrid(3 * DMODEL / 128, M_TOK / 128);   // (24, 64)
    gemm_qkv<<<qkvgrid, 256, 0, stream>>>(xb, wstack, bq, bk, bv, cs, sn, qbf, kbf, vtb);

    dim3 agrid(BATCH * NH, S_LEN / 256);           // (64 heads, 8 qblocks)
    attn_mfma3<<<agrid, 512, 0, stream>>>(qbf, kbf, vtb, biasG, flagmask, ctxb);

    dim3 ogrid(DMODEL / 128, M_TOK / 128);         // (8, 64)
    gemm_out<<<ogrid, 256, 0, stream>>>(ctxb, wto, bo, mask, out);
}